// Round 1
// baseline (1032.803 us; speedup 1.0000x reference)
//
#include <hip/hip_runtime.h>
#include <math.h>

#define DI 512
#define DM 256
#define LSEQ 1024
#define BB 4
#define NST 64
#define ROWS (BB*LSEQ)   // 4096

__device__ __forceinline__ float siluf(float x) {
    return x / (1.f + __expf(-x));
}

__device__ __forceinline__ float softplusf(float x) {
    return (x > 20.f) ? x : log1pf(__expf(x));
}

// ---------------- LayerNorm: one wave per row of 256 ----------------
__global__ __launch_bounds__(256) void ln_kernel(
    const float* __restrict__ x, const float* __restrict__ g,
    const float* __restrict__ b, float* __restrict__ xn)
{
    int lane = threadIdx.x & 63;
    int row = blockIdx.x * 4 + (threadIdx.x >> 6);
    const float4* xr = (const float4*)(x + (size_t)row * DM);
    float4 v = xr[lane];
    float s = v.x + v.y + v.z + v.w;
    #pragma unroll
    for (int o = 32; o; o >>= 1) s += __shfl_xor(s, o, 64);
    float mu = s * (1.f / DM);
    float dx = v.x - mu, dy = v.y - mu, dz = v.z - mu, dw = v.w - mu;
    float q = dx*dx + dy*dy + dz*dz + dw*dw;
    #pragma unroll
    for (int o = 32; o; o >>= 1) q += __shfl_xor(q, o, 64);
    float inv = rsqrtf(q * (1.f / DM) + 1e-5f);
    float4 gv = ((const float4*)g)[lane];
    float4 bv = ((const float4*)b)[lane];
    float4 o4;
    o4.x = dx * inv * gv.x + bv.x;
    o4.y = dy * inv * gv.y + bv.y;
    o4.z = dz * inv * gv.z + bv.z;
    o4.w = dw * inv * gv.w + bv.w;
    ((float4*)(xn + (size_t)row * DM))[lane] = o4;
}

// ---------------- fp32 tiled GEMM: C[M,N] = A[M,K] @ W[N,K]^T --------
// modes: 0 plain, 1 split (n<512 -> C, else C2), 2 softplus(acc+aux[n]),
//        3 acc + aux[m*N+n] (residual)
__global__ __launch_bounds__(256) void gemm_tn(
    const float* __restrict__ A, int lda,
    const float* __restrict__ W,
    float* __restrict__ C, float* __restrict__ C2,
    const float* __restrict__ aux,
    int M, int N, int K, int mode)
{
    __shared__ float As[16][68];
    __shared__ float Ws[16][68];
    const int bm = blockIdx.y * 64;
    const int bn = blockIdx.x * 64;
    const int tid = threadIdx.x;
    const int tx = tid & 15;
    const int ty = tid >> 4;
    const int lr = tid >> 2;          // 0..63 row within tile
    const int lc = (tid & 3) << 2;    // 0,4,8,12 k-offset
    const bool wok = (bn + lr) < N;
    float acc[4][4] = {};

    for (int k0 = 0; k0 < K; k0 += 16) {
        float4 av = *(const float4*)(A + (size_t)(bm + lr) * lda + k0 + lc);
        float4 wv = make_float4(0.f, 0.f, 0.f, 0.f);
        if (wok) wv = *(const float4*)(W + (size_t)(bn + lr) * K + k0 + lc);
        __syncthreads();
        As[lc+0][lr] = av.x; As[lc+1][lr] = av.y; As[lc+2][lr] = av.z; As[lc+3][lr] = av.w;
        Ws[lc+0][lr] = wv.x; Ws[lc+1][lr] = wv.y; Ws[lc+2][lr] = wv.z; Ws[lc+3][lr] = wv.w;
        __syncthreads();
        #pragma unroll
        for (int k = 0; k < 16; ++k) {
            float a[4], w[4];
            #pragma unroll
            for (int i = 0; i < 4; ++i) a[i] = As[k][ty*4 + i];
            #pragma unroll
            for (int j = 0; j < 4; ++j) w[j] = Ws[k][tx*4 + j];
            #pragma unroll
            for (int i = 0; i < 4; ++i)
                #pragma unroll
                for (int j = 0; j < 4; ++j)
                    acc[i][j] = fmaf(a[i], w[j], acc[i][j]);
        }
    }

    #pragma unroll
    for (int i = 0; i < 4; ++i) {
        int m = bm + ty*4 + i;
        #pragma unroll
        for (int j = 0; j < 4; ++j) {
            int n = bn + tx*4 + j;
            if (n >= N) continue;
            float v = acc[i][j];
            if (mode == 0) {
                C[(size_t)m * N + n] = v;
            } else if (mode == 1) {
                if (n < 512) C[(size_t)m * 512 + n] = v;
                else         C2[(size_t)m * 512 + (n - 512)] = v;
            } else if (mode == 2) {
                C[(size_t)m * N + n] = softplusf(v + aux[n]);
            } else {
                C[(size_t)m * N + n] = v + aux[(size_t)m * N + n];
            }
        }
    }
}

// ---------------- causal depthwise conv (k=4) + SiLU ----------------
__global__ __launch_bounds__(256) void conv_silu_kernel(
    const float* __restrict__ xm, const float* __restrict__ cw,
    const float* __restrict__ cb, float* __restrict__ xc)
{
    int idx = blockIdx.x * 256 + threadIdx.x;   // over ROWS*DI
    int d = idx & (DI - 1);
    int row = idx >> 9;
    int t = row & (LSEQ - 1);
    float w0 = cw[d*4+0], w1 = cw[d*4+1], w2 = cw[d*4+2], w3 = cw[d*4+3];
    float acc = cb[d];
    const float* p = xm + (size_t)row * DI + d;
    if (t >= 3) {
        acc += p[-3*DI]*w0 + p[-2*DI]*w1 + p[-1*DI]*w2 + p[0]*w3;
    } else {
        if (t >= 3) acc += p[-3*DI]*w0;
        if (t >= 2) acc += p[-2*DI]*w1;
        if (t >= 1) acc += p[-1*DI]*w2;
        acc += p[0]*w3;
    }
    xc[idx] = siluf(acc);
}

// ---------------- SSM scan: one wave per (b,d); lane = state n ------
__global__ __launch_bounds__(256) void scan_kernel(
    const float* __restrict__ dt, const float* __restrict__ xc,
    const float* __restrict__ dbl, const float* __restrict__ z,
    const float* __restrict__ A_log, const float* __restrict__ Dp,
    float* __restrict__ y)
{
    int wid = (blockIdx.x * 256 + threadIdx.x) >> 6;
    int lane = threadIdx.x & 63;
    int b = wid >> 9;
    int d = wid & 511;
    float Al2 = -__expf(A_log[d * NST + lane]) * 1.44269504f;  // A * log2(e)
    float dpd = Dp[d];
    const size_t rb = (size_t)b * LSEQ;
    float h = 0.f;
    float dt4[4] = {}, u4[4] = {}, z4[4] = {}, B4[4] = {}, C4[4] = {};
    #pragma unroll
    for (int q = 0; q < 4; ++q) {
        size_t row = rb + q;
        dt4[q] = dt[row*DI + d];
        u4[q]  = xc[row*DI + d];
        z4[q]  = z[row*DI + d];
        B4[q]  = dbl[row*144 + 16 + lane];
        C4[q]  = dbl[row*144 + 80 + lane];
    }
    for (int t0 = 0; t0 < LSEQ; t0 += 4) {
        float ndt[4] = {}, nu[4] = {}, nz[4] = {}, nB[4] = {}, nC[4] = {};
        if (t0 + 4 < LSEQ) {
            #pragma unroll
            for (int q = 0; q < 4; ++q) {
                size_t row = rb + t0 + 4 + q;
                ndt[q] = dt[row*DI + d];
                nu[q]  = xc[row*DI + d];
                nz[q]  = z[row*DI + d];
                nB[q]  = dbl[row*144 + 16 + lane];
                nC[q]  = dbl[row*144 + 80 + lane];
            }
        }
        #pragma unroll
        for (int q = 0; q < 4; ++q) {
            float dA = exp2f(dt4[q] * Al2);
            h = fmaf(dA, h, dt4[q] * u4[q] * B4[q]);
            float s = h * C4[q];
            #pragma unroll
            for (int o = 32; o; o >>= 1) s += __shfl_xor(s, o, 64);
            if (lane == 0) {
                size_t row = rb + t0 + q;
                y[row*DI + d] = (s + u4[q]*dpd) * siluf(z4[q]);
            }
        }
        #pragma unroll
        for (int q = 0; q < 4; ++q) {
            dt4[q]=ndt[q]; u4[q]=nu[q]; z4[q]=nz[q]; B4[q]=nB[q]; C4[q]=nC[q];
        }
    }
}

extern "C" void kernel_launch(void* const* d_in, const int* in_sizes, int n_in,
                              void* d_out, int out_size, void* d_ws, size_t ws_size,
                              hipStream_t stream)
{
    const float* x      = (const float*)d_in[0];
    const float* ln_g   = (const float*)d_in[1];
    const float* ln_b   = (const float*)d_in[2];
    const float* in_w   = (const float*)d_in[3];
    const float* conv_w = (const float*)d_in[4];
    const float* conv_b = (const float*)d_in[5];
    const float* xp_w   = (const float*)d_in[6];
    const float* dt_w   = (const float*)d_in[7];
    const float* dt_b   = (const float*)d_in[8];
    const float* A_log  = (const float*)d_in[9];
    const float* Dp     = (const float*)d_in[10];
    const float* out_w  = (const float*)d_in[11];
    float* out = (float*)d_out;

    char* ws = (char*)d_ws;
    float* xn  = (float*)(ws);                       // 4096*256  (4 MiB)
    float* xm  = (float*)(ws + (size_t)( 4u<<20));   // 4096*512  (8 MiB) ; reused as y
    float* zb  = (float*)(ws + (size_t)(12u<<20));   // 4096*512
    float* xcb = (float*)(ws + (size_t)(20u<<20));   // 4096*512
    float* dblb= (float*)(ws + (size_t)(28u<<20));   // 4096*144  (2.25 MiB)
    float* dtb = (float*)(ws + (size_t)(31u<<20));   // 4096*512
    float* yb  = xm;

    for (int l = 0; l < 2; ++l) {
        const float* xin = (l == 0) ? x : out;
        ln_kernel<<<ROWS/4, 256, 0, stream>>>(xin, ln_g + l*DM, ln_b + l*DM, xn);
        // in_proj: [4096,256] @ [1024,256]^T -> split xm | z
        gemm_tn<<<dim3(1024/64, ROWS/64), 256, 0, stream>>>(
            xn, DM, in_w + (size_t)l*1024*DM, xm, zb, nullptr, ROWS, 1024, DM, 1);
        conv_silu_kernel<<<(ROWS*DI)/256, 256, 0, stream>>>(
            xm, conv_w + (size_t)l*DI*4, conv_b + (size_t)l*DI, xcb);
        // x_proj: [4096,512] @ [144,512]^T -> dbl
        gemm_tn<<<dim3((144+63)/64, ROWS/64), 256, 0, stream>>>(
            xcb, DI, xp_w + (size_t)l*144*DI, dblb, nullptr, nullptr, ROWS, 144, DI, 0);
        // dt: [4096,16] @ [512,16]^T + bias -> softplus
        gemm_tn<<<dim3(DI/64, ROWS/64), 256, 0, stream>>>(
            dblb, 144, dt_w + (size_t)l*DI*16, dtb, nullptr, dt_b + (size_t)l*DI,
            ROWS, DI, 16, 2);
        scan_kernel<<<(BB*DI)/4, 256, 0, stream>>>(
            dtb, xcb, dblb, zb, A_log + (size_t)l*DI*NST, Dp + (size_t)l*DI, yb);
        // out_proj + residual: [4096,512] @ [256,512]^T + xin
        gemm_tn<<<dim3(DM/64, ROWS/64), 256, 0, stream>>>(
            yb, DI, out_w + (size_t)l*DM*DI, out, nullptr, xin, ROWS, DM, DI, 3);
    }
}

// Round 3
// 526.596 us; speedup vs baseline: 1.9613x; 1.9613x over previous
//
#include <hip/hip_runtime.h>
#include <math.h>

#define DI 512
#define DM 256
#define LSEQ 1024
#define BB 4
#define NST 64
#define ROWS (BB*LSEQ)   // 4096
#define NC 16            // chunks per sequence
#define CL 64            // chunk length

__device__ __forceinline__ float fexp2(float x) {
    return __builtin_exp2f(x);
}
__device__ __forceinline__ float siluf(float x) { return x / (1.f + __expf(-x)); }
__device__ __forceinline__ float softplusf(float x) { return (x > 20.f) ? x : log1pf(__expf(x)); }
__device__ __forceinline__ float rlane(float v, int l) {
    return __int_as_float(__builtin_amdgcn_readlane(__float_as_int(v), l));
}
#define DPP_ADD(v, ctrl) \
    v += __int_as_float(__builtin_amdgcn_update_dpp(0, __float_as_int(v), ctrl, 0xF, 0xF, true))
__device__ __forceinline__ float wave_sum63(float v) {
    DPP_ADD(v, 0x111);  // row_shr:1
    DPP_ADD(v, 0x112);  // row_shr:2
    DPP_ADD(v, 0x114);  // row_shr:4
    DPP_ADD(v, 0x118);  // row_shr:8  -> lane 16r+15 = row sum
    DPP_ADD(v, 0x142);  // row_bcast:15 -> lane31=r0+r1, lane63=r2+r3
    DPP_ADD(v, 0x143);  // row_bcast:31 -> lane63 = total
    return v;
}

// ---------------- LayerNorm: one wave per row of 256 ----------------
__global__ __launch_bounds__(256) void ln_kernel(
    const float* __restrict__ x, const float* __restrict__ g,
    const float* __restrict__ b, float* __restrict__ xn)
{
    int lane = threadIdx.x & 63;
    int row = blockIdx.x * 4 + (threadIdx.x >> 6);
    const float4* xr = (const float4*)(x + (size_t)row * DM);
    float4 v = xr[lane];
    float s = v.x + v.y + v.z + v.w;
    #pragma unroll
    for (int o = 32; o; o >>= 1) s += __shfl_xor(s, o, 64);
    float mu = s * (1.f / DM);
    float dx = v.x - mu, dy = v.y - mu, dz = v.z - mu, dw = v.w - mu;
    float q = dx*dx + dy*dy + dz*dz + dw*dw;
    #pragma unroll
    for (int o = 32; o; o >>= 1) q += __shfl_xor(q, o, 64);
    float inv = rsqrtf(q * (1.f / DM) + 1e-5f);
    float4 gv = ((const float4*)g)[lane];
    float4 bv = ((const float4*)b)[lane];
    float4 o4;
    o4.x = dx * inv * gv.x + bv.x;
    o4.y = dy * inv * gv.y + bv.y;
    o4.z = dz * inv * gv.z + bv.z;
    o4.w = dw * inv * gv.w + bv.w;
    ((float4*)(xn + (size_t)row * DM))[lane] = o4;
}

// ---------------- fp32 tiled GEMM: C[M,N] = A[M,K] @ W[N,K]^T --------
// modes: 0 plain, 1 split (n<512 -> C, else C2), 2 softplus(acc+aux[n])
__global__ __launch_bounds__(256) void gemm_tn(
    const float* __restrict__ A, int lda,
    const float* __restrict__ W,
    float* __restrict__ C, float* __restrict__ C2,
    const float* __restrict__ aux,
    int M, int N, int K, int mode)
{
    __shared__ float As[16][68];
    __shared__ float Ws[16][68];
    const int bm = blockIdx.y * 64;
    const int bn = blockIdx.x * 64;
    const int tid = threadIdx.x;
    const int tx = tid & 15;
    const int ty = tid >> 4;
    const int lr = tid >> 2;
    const int lc = (tid & 3) << 2;
    const bool wok = (bn + lr) < N;
    float acc[4][4] = {};

    for (int k0 = 0; k0 < K; k0 += 16) {
        float4 av = *(const float4*)(A + (size_t)(bm + lr) * lda + k0 + lc);
        float4 wv = make_float4(0.f, 0.f, 0.f, 0.f);
        if (wok) wv = *(const float4*)(W + (size_t)(bn + lr) * K + k0 + lc);
        __syncthreads();
        As[lc+0][lr] = av.x; As[lc+1][lr] = av.y; As[lc+2][lr] = av.z; As[lc+3][lr] = av.w;
        Ws[lc+0][lr] = wv.x; Ws[lc+1][lr] = wv.y; Ws[lc+2][lr] = wv.z; Ws[lc+3][lr] = wv.w;
        __syncthreads();
        #pragma unroll
        for (int k = 0; k < 16; ++k) {
            float a[4], w[4];
            #pragma unroll
            for (int i = 0; i < 4; ++i) a[i] = As[k][ty*4 + i];
            #pragma unroll
            for (int j = 0; j < 4; ++j) w[j] = Ws[k][tx*4 + j];
            #pragma unroll
            for (int i = 0; i < 4; ++i)
                #pragma unroll
                for (int j = 0; j < 4; ++j)
                    acc[i][j] = fmaf(a[i], w[j], acc[i][j]);
        }
    }

    #pragma unroll
    for (int i = 0; i < 4; ++i) {
        int m = bm + ty*4 + i;
        #pragma unroll
        for (int j = 0; j < 4; ++j) {
            int n = bn + tx*4 + j;
            if (n >= N) continue;
            float v = acc[i][j];
            if (mode == 0) {
                C[(size_t)m * N + n] = v;
            } else if (mode == 1) {
                if (n < 512) C[(size_t)m * 512 + n] = v;
                else         C2[(size_t)m * 512 + (n - 512)] = v;
            } else {
                C[(size_t)m * N + n] = softplusf(v + aux[n]);
            }
        }
    }
}

// ------------ GEMM with transposed A: C[M,N] = AT^T @ W^T + res ------
// AT is [K][M] row-major (ld = M)
__global__ __launch_bounds__(256) void gemm_at(
    const float* __restrict__ AT,
    const float* __restrict__ W,
    float* __restrict__ C,
    const float* __restrict__ res,
    int M, int N, int K)
{
    __shared__ float As[16][68];
    __shared__ float Ws[16][68];
    const int bm = blockIdx.y * 64;
    const int bn = blockIdx.x * 64;
    const int tid = threadIdx.x;
    const int tx = tid & 15;
    const int ty = tid >> 4;
    const int lr = tid >> 2;
    const int lc = (tid & 3) << 2;
    float acc[4][4] = {};

    for (int k0 = 0; k0 < K; k0 += 16) {
        float4 av = *(const float4*)(AT + (size_t)(k0 + ty) * M + bm + tx * 4);
        float4 wv = *(const float4*)(W + (size_t)(bn + lr) * K + k0 + lc);
        __syncthreads();
        *(float4*)&As[ty][tx * 4] = av;
        Ws[lc+0][lr] = wv.x; Ws[lc+1][lr] = wv.y; Ws[lc+2][lr] = wv.z; Ws[lc+3][lr] = wv.w;
        __syncthreads();
        #pragma unroll
        for (int k = 0; k < 16; ++k) {
            float a[4], w[4];
            #pragma unroll
            for (int i = 0; i < 4; ++i) a[i] = As[k][ty*4 + i];
            #pragma unroll
            for (int j = 0; j < 4; ++j) w[j] = Ws[k][tx*4 + j];
            #pragma unroll
            for (int i = 0; i < 4; ++i)
                #pragma unroll
                for (int j = 0; j < 4; ++j)
                    acc[i][j] = fmaf(a[i], w[j], acc[i][j]);
        }
    }

    #pragma unroll
    for (int i = 0; i < 4; ++i) {
        int m = bm + ty*4 + i;
        #pragma unroll
        for (int j = 0; j < 4; ++j) {
            int n = bn + tx*4 + j;
            C[(size_t)m * N + n] = acc[i][j] + res[(size_t)m * N + n];
        }
    }
}

// ---------------- causal depthwise conv (k=4) + SiLU ----------------
__global__ __launch_bounds__(256) void conv_silu_kernel(
    const float* __restrict__ xm, const float* __restrict__ cw,
    const float* __restrict__ cb, float* __restrict__ xc)
{
    int idx = blockIdx.x * 256 + threadIdx.x;
    int d = idx & (DI - 1);
    int row = idx >> 9;
    int t = row & (LSEQ - 1);
    float w0 = cw[d*4+0], w1 = cw[d*4+1], w2 = cw[d*4+2], w3 = cw[d*4+3];
    float acc = cb[d];
    const float* p = xm + (size_t)row * DI + d;
    if (t >= 3) {
        acc += p[-3*DI]*w0 + p[-2*DI]*w1 + p[-1*DI]*w2 + p[0]*w3;
    } else {
        if (t >= 2) acc += p[-2*DI]*w1;
        if (t >= 1) acc += p[-1*DI]*w2;
        acc += p[0]*w3;
    }
    xc[idx] = siluf(acc);
}

// -------- scan pass 1: per-chunk (P_end, H_end) with h0 = 0 ----------
// wave = (b, d, c); lane = state n
__global__ __launch_bounds__(256) void scan_p1(
    const float* __restrict__ dt, const float* __restrict__ xc,
    const float* __restrict__ dbl, const float* __restrict__ A_log,
    float* __restrict__ Pe, float* __restrict__ He)
{
    int wid = (blockIdx.x * 256 + threadIdx.x) >> 6;
    int lane = threadIdx.x & 63;
    int c = wid & (NC - 1);
    int d = (wid >> 4) & (DI - 1);
    int b = wid >> 13;
    float Al2 = -__expf(A_log[d * NST + lane]) * 1.44269504f;
    size_t row0 = (size_t)b * LSEQ + (size_t)c * CL;
    float dtv = dt[(row0 + lane) * DI + d];
    float uv  = xc[(row0 + lane) * DI + d];
    float duv = dtv * uv;
    const float* bp = dbl + row0 * 144 + 16 + lane;
    float P = 1.f, H = 0.f;
    float Bv[8], Bn[8];
    #pragma unroll
    for (int q = 0; q < 8; ++q) Bv[q] = bp[q * 144];
    for (int t0 = 0; t0 < CL; t0 += 8) {
        if (t0 + 8 < CL) {
            #pragma unroll
            for (int q = 0; q < 8; ++q) Bn[q] = bp[(t0 + 8 + q) * 144];
        }
        #pragma unroll
        for (int q = 0; q < 8; ++q) {
            int t = t0 + q;
            float dts = rlane(dtv, t);
            float dus = rlane(duv, t);
            float dA = fexp2(dts * Al2);
            P *= dA;
            H = fmaf(dA, H, dus * Bv[q]);
        }
        #pragma unroll
        for (int q = 0; q < 8; ++q) Bv[q] = Bn[q];
    }
    size_t o = (size_t)wid * 64 + lane;
    Pe[o] = P;
    He[o] = H;
}

// -------- scan pass 2: recombine carries, recompute, emit yT ---------
__global__ __launch_bounds__(256) void scan_p2(
    const float* __restrict__ dt, const float* __restrict__ xc,
    const float* __restrict__ dbl, const float* __restrict__ z,
    const float* __restrict__ A_log, const float* __restrict__ Dp,
    const float* __restrict__ Pe, const float* __restrict__ He,
    float* __restrict__ yT)
{
    int wid = (blockIdx.x * 256 + threadIdx.x) >> 6;
    int lane = threadIdx.x & 63;
    int c = wid & (NC - 1);
    int d = (wid >> 4) & (DI - 1);
    int b = wid >> 13;
    // carry-in: sequential combine of chunks 0..c-1
    float h = 0.f;
    int base = (b << 13) + (d << 4);
    for (int j = 0; j < c; ++j) {
        size_t o = (size_t)(base + j) * 64 + lane;
        h = fmaf(Pe[o], h, He[o]);
    }
    float Al2 = -__expf(A_log[d * NST + lane]) * 1.44269504f;
    size_t row0 = (size_t)b * LSEQ + (size_t)c * CL;
    float dtv = dt[(row0 + lane) * DI + d];
    float uv  = xc[(row0 + lane) * DI + d];
    float zv  = z[(row0 + lane) * DI + d];
    float duv = dtv * uv;
    const float* bp = dbl + row0 * 144 + 16 + lane;
    const float* cp = dbl + row0 * 144 + 80 + lane;
    float Bv[8], Cv[8], Bn[8], Cn[8];
    #pragma unroll
    for (int q = 0; q < 8; ++q) { Bv[q] = bp[q * 144]; Cv[q] = cp[q * 144]; }
    float yv = 0.f;
    for (int t0 = 0; t0 < CL; t0 += 8) {
        if (t0 + 8 < CL) {
            #pragma unroll
            for (int q = 0; q < 8; ++q) {
                Bn[q] = bp[(t0 + 8 + q) * 144];
                Cn[q] = cp[(t0 + 8 + q) * 144];
            }
        }
        #pragma unroll
        for (int q = 0; q < 8; ++q) {
            int t = t0 + q;
            float dts = rlane(dtv, t);
            float dus = rlane(duv, t);
            float dA = fexp2(dts * Al2);
            h = fmaf(dA, h, dus * Bv[q]);
            float s = h * Cv[q];
            s = wave_sum63(s);
            float tot = rlane(s, 63);
            if (lane == t) yv = tot;
        }
        #pragma unroll
        for (int q = 0; q < 8; ++q) { Bv[q] = Bn[q]; Cv[q] = Cn[q]; }
    }
    float y = (yv + uv * Dp[d]) * siluf(zv);
    yT[(size_t)d * ROWS + row0 + lane] = y;
}

extern "C" void kernel_launch(void* const* d_in, const int* in_sizes, int n_in,
                              void* d_out, int out_size, void* d_ws, size_t ws_size,
                              hipStream_t stream)
{
    const float* x      = (const float*)d_in[0];
    const float* ln_g   = (const float*)d_in[1];
    const float* ln_b   = (const float*)d_in[2];
    const float* in_w   = (const float*)d_in[3];
    const float* conv_w = (const float*)d_in[4];
    const float* conv_b = (const float*)d_in[5];
    const float* xp_w   = (const float*)d_in[6];
    const float* dt_w   = (const float*)d_in[7];
    const float* dt_b   = (const float*)d_in[8];
    const float* A_log  = (const float*)d_in[9];
    const float* Dp     = (const float*)d_in[10];
    const float* out_w  = (const float*)d_in[11];
    float* out = (float*)d_out;

    char* ws = (char*)d_ws;
    float* xn  = (float*)(ws);                        // 4096*256, dead after in_proj
    float* dblb= (float*)(ws);                        // 4096*144, written after xn dead
    float* xm  = (float*)(ws + (size_t)( 4u<<20));    // 4096*512, dead after conv
    float* Pe  = (float*)(ws + (size_t)( 4u<<20));    // 32768*64, written after xm dead
    float* zb  = (float*)(ws + (size_t)(12u<<20));    // 4096*512
    float* xcb = (float*)(ws + (size_t)(20u<<20));    // 4096*512
    float* dtb = (float*)(ws + (size_t)(28u<<20));    // 4096*512
    float* yT  = (float*)(ws + (size_t)(36u<<20));    // 512*4096 (transposed)
    float* He  = (float*)(ws + (size_t)(44u<<20));    // 32768*64

    for (int l = 0; l < 2; ++l) {
        const float* xin = (l == 0) ? x : out;
        ln_kernel<<<ROWS/4, 256, 0, stream>>>(xin, ln_g + l*DM, ln_b + l*DM, xn);
        // in_proj: [4096,256] @ [1024,256]^T -> split xm | z
        gemm_tn<<<dim3(1024/64, ROWS/64), 256, 0, stream>>>(
            xn, DM, in_w + (size_t)l*1024*DM, xm, zb, nullptr, ROWS, 1024, DM, 1);
        conv_silu_kernel<<<(ROWS*DI)/256, 256, 0, stream>>>(
            xm, conv_w + (size_t)l*DI*4, conv_b + (size_t)l*DI, xcb);
        // x_proj: [4096,512] @ [144,512]^T -> dbl
        gemm_tn<<<dim3((144+63)/64, ROWS/64), 256, 0, stream>>>(
            xcb, DI, xp_w + (size_t)l*144*DI, dblb, nullptr, nullptr, ROWS, 144, DI, 0);
        // dt: [4096,16] @ [512,16]^T + bias -> softplus
        gemm_tn<<<dim3(DI/64, ROWS/64), 256, 0, stream>>>(
            dblb, 144, dt_w + (size_t)l*DI*16, dtb, nullptr, dt_b + (size_t)l*DI,
            ROWS, DI, 16, 2);
        // chunked scan
        scan_p1<<<(BB*DI*NC)/4, 256, 0, stream>>>(
            dtb, xcb, dblb, A_log + (size_t)l*DI*NST, Pe, He);
        scan_p2<<<(BB*DI*NC)/4, 256, 0, stream>>>(
            dtb, xcb, dblb, zb, A_log + (size_t)l*DI*NST, Dp + (size_t)l*DI,
            Pe, He, yT);
        // out_proj + residual: yT^T @ out_w^T + xin
        gemm_at<<<dim3(DM/64, ROWS/64), 256, 0, stream>>>(
            yT, out_w + (size_t)l*DM*DI, out, xin, ROWS, DM, DI);
    }
}

// Round 4
// 447.425 us; speedup vs baseline: 2.3083x; 1.1769x over previous
//
#include <hip/hip_runtime.h>
#include <math.h>

#define DI 512
#define DM 256
#define LSEQ 1024
#define BB 4
#define NST 64
#define ROWS (BB*LSEQ)   // 4096
#define NC 16            // chunks per sequence
#define CL 64            // chunk length

typedef __bf16 bf16x8 __attribute__((ext_vector_type(8)));
typedef __bf16 bf16x4 __attribute__((ext_vector_type(4)));
typedef float f32x4 __attribute__((ext_vector_type(4)));
typedef unsigned short u16;
typedef u16 u16x8 __attribute__((ext_vector_type(8)));

__device__ __forceinline__ float siluf(float x) { return x / (1.f + __expf(-x)); }
__device__ __forceinline__ float softplusf(float x) { return (x > 20.f) ? x : log1pf(__expf(x)); }
__device__ __forceinline__ float rlane(float v, int l) {
    return __int_as_float(__builtin_amdgcn_readlane(__float_as_int(v), l));
}
#define DPP_ADD(v, ctrl) \
    v += __int_as_float(__builtin_amdgcn_update_dpp(0, __float_as_int(v), ctrl, 0xF, 0xF, true))
__device__ __forceinline__ float wave_sum63(float v) {
    DPP_ADD(v, 0x111);  // row_shr:1
    DPP_ADD(v, 0x112);  // row_shr:2
    DPP_ADD(v, 0x114);  // row_shr:4
    DPP_ADD(v, 0x118);  // row_shr:8
    DPP_ADD(v, 0x142);  // row_bcast:15
    DPP_ADD(v, 0x143);  // row_bcast:31 -> lane63 = total
    return v;
}

// ---------------- float -> bf16 convert (weights) -------------------
__global__ __launch_bounds__(256) void f2bf(
    const float* __restrict__ in, __bf16* __restrict__ out, int n)
{
    int i = (blockIdx.x * 256 + threadIdx.x) * 4;
    if (i >= n) return;
    float4 v = *(const float4*)(in + i);
    bf16x4 o;
    o[0] = (__bf16)v.x; o[1] = (__bf16)v.y; o[2] = (__bf16)v.z; o[3] = (__bf16)v.w;
    *(bf16x4*)(out + i) = o;
}

// ---------------- LayerNorm: one wave per row of 256, bf16 out ------
__global__ __launch_bounds__(256) void ln_kernel(
    const float* __restrict__ x, const float* __restrict__ g,
    const float* __restrict__ b, __bf16* __restrict__ xn)
{
    int lane = threadIdx.x & 63;
    int row = blockIdx.x * 4 + (threadIdx.x >> 6);
    const float4* xr = (const float4*)(x + (size_t)row * DM);
    float4 v = xr[lane];
    float s = v.x + v.y + v.z + v.w;
    #pragma unroll
    for (int o = 32; o; o >>= 1) s += __shfl_xor(s, o, 64);
    float mu = s * (1.f / DM);
    float dx = v.x - mu, dy = v.y - mu, dz = v.z - mu, dw = v.w - mu;
    float q = dx*dx + dy*dy + dz*dz + dw*dw;
    #pragma unroll
    for (int o = 32; o; o >>= 1) q += __shfl_xor(q, o, 64);
    float inv = rsqrtf(q * (1.f / DM) + 1e-5f);
    float4 gv = ((const float4*)g)[lane];
    float4 bv = ((const float4*)b)[lane];
    bf16x4 o4;
    o4[0] = (__bf16)(dx * inv * gv.x + bv.x);
    o4[1] = (__bf16)(dy * inv * gv.y + bv.y);
    o4[2] = (__bf16)(dz * inv * gv.z + bv.z);
    o4[3] = (__bf16)(dw * inv * gv.w + bv.w);
    *(bf16x4*)(xn + (size_t)row * DM + lane * 4) = o4;
}

// ------------- bf16 MFMA GEMM: C[M,N] = A[M,K] @ W[N,K]^T -----------
// block 256 = 4 waves (2x2); tile 128(M) x 64(N); wave subtile 64x32.
// mode 0: fp32 store (col guard, ldc=N)
// mode 1: split at 512 -> C (ld 512) / C2 (ld 512)
// mode 2: fp32 store + res add (ldc=N)
template<int KK>
__global__ __launch_bounds__(256) void gemm_mfma(
    const __bf16* __restrict__ A, const __bf16* __restrict__ W,
    float* __restrict__ C, float* __restrict__ C2,
    const float* __restrict__ res, int N, int mode)
{
    int wid = threadIdx.x >> 6, lane = threadIdx.x & 63;
    int wr = wid >> 1, wc = wid & 1;
    int bm = blockIdx.y * 128, bn = blockIdx.x * 64;
    int l15 = lane & 15, lk = (lane >> 4) * 8;
    const __bf16* Ap = A + (size_t)(bm + wr*64 + l15) * KK + lk;
    int wrow0 = bn + wc*32 + l15;
    int wrow1 = wrow0 + 16;
    if (wrow0 > N-1) wrow0 = N-1;
    if (wrow1 > N-1) wrow1 = N-1;
    const __bf16* Wp0 = W + (size_t)wrow0 * KK + lk;
    const __bf16* Wp1 = W + (size_t)wrow1 * KK + lk;
    f32x4 acc[4][2] = {};
    #pragma unroll 4
    for (int k0 = 0; k0 < KK; k0 += 32) {
        bf16x8 b0 = *(const bf16x8*)(Wp0 + k0);
        bf16x8 b1 = *(const bf16x8*)(Wp1 + k0);
        #pragma unroll
        for (int m = 0; m < 4; ++m) {
            bf16x8 a = *(const bf16x8*)(Ap + (size_t)m*16*KK + k0);
            acc[m][0] = __builtin_amdgcn_mfma_f32_16x16x32_bf16(a, b0, acc[m][0], 0, 0, 0);
            acc[m][1] = __builtin_amdgcn_mfma_f32_16x16x32_bf16(a, b1, acc[m][1], 0, 0, 0);
        }
    }
    int r4 = (lane >> 4) * 4;
    #pragma unroll
    for (int m = 0; m < 4; ++m) {
        int row = bm + wr*64 + m*16 + r4;
        #pragma unroll
        for (int n = 0; n < 2; ++n) {
            int col = bn + wc*32 + n*16 + l15;
            #pragma unroll
            for (int r = 0; r < 4; ++r) {
                float v = acc[m][n][r];
                int rr = row + r;
                if (mode == 0) {
                    if (col < N) C[(size_t)rr * N + col] = v;
                } else if (mode == 1) {
                    if (col < 512) C[(size_t)rr * 512 + col] = v;
                    else           C2[(size_t)rr * 512 + col - 512] = v;
                } else {
                    C[(size_t)rr * N + col] = v + res[(size_t)rr * N + col];
                }
            }
        }
    }
}

// -------- fp32 tiled GEMM (dt projection only, K=16) ----------------
__global__ __launch_bounds__(256) void gemm_tn(
    const float* __restrict__ A, int lda,
    const float* __restrict__ W,
    float* __restrict__ C, const float* __restrict__ aux,
    int M, int N, int K)
{
    __shared__ float As[16][68];
    __shared__ float Ws[16][68];
    const int bm = blockIdx.y * 64;
    const int bn = blockIdx.x * 64;
    const int tid = threadIdx.x;
    const int tx = tid & 15;
    const int ty = tid >> 4;
    const int lr = tid >> 2;
    const int lc = (tid & 3) << 2;
    float acc[4][4] = {};

    for (int k0 = 0; k0 < K; k0 += 16) {
        float4 av = *(const float4*)(A + (size_t)(bm + lr) * lda + k0 + lc);
        float4 wv = *(const float4*)(W + (size_t)(bn + lr) * K + k0 + lc);
        __syncthreads();
        As[lc+0][lr] = av.x; As[lc+1][lr] = av.y; As[lc+2][lr] = av.z; As[lc+3][lr] = av.w;
        Ws[lc+0][lr] = wv.x; Ws[lc+1][lr] = wv.y; Ws[lc+2][lr] = wv.z; Ws[lc+3][lr] = wv.w;
        __syncthreads();
        #pragma unroll
        for (int k = 0; k < 16; ++k) {
            float a[4], w[4];
            #pragma unroll
            for (int i = 0; i < 4; ++i) a[i] = As[k][ty*4 + i];
            #pragma unroll
            for (int j = 0; j < 4; ++j) w[j] = Ws[k][tx*4 + j];
            #pragma unroll
            for (int i = 0; i < 4; ++i)
                #pragma unroll
                for (int j = 0; j < 4; ++j)
                    acc[i][j] = fmaf(a[i], w[j], acc[i][j]);
        }
    }

    #pragma unroll
    for (int i = 0; i < 4; ++i) {
        int m = bm + ty*4 + i;
        #pragma unroll
        for (int j = 0; j < 4; ++j) {
            int n = bn + tx*4 + j;
            C[(size_t)m * N + n] = softplusf(acc[i][j] + aux[n]);
        }
    }
}

// ---------------- causal depthwise conv (k=4) + SiLU ----------------
__global__ __launch_bounds__(256) void conv_silu_kernel(
    const float* __restrict__ xm, const float* __restrict__ cw,
    const float* __restrict__ cb, float* __restrict__ xc,
    __bf16* __restrict__ xcb)
{
    int idx = blockIdx.x * 256 + threadIdx.x;
    int d = idx & (DI - 1);
    int row = idx >> 9;
    int t = row & (LSEQ - 1);
    float w0 = cw[d*4+0], w1 = cw[d*4+1], w2 = cw[d*4+2], w3 = cw[d*4+3];
    float acc = cb[d];
    const float* p = xm + (size_t)row * DI + d;
    if (t >= 3) {
        acc += p[-3*DI]*w0 + p[-2*DI]*w1 + p[-1*DI]*w2 + p[0]*w3;
    } else {
        if (t >= 2) acc += p[-2*DI]*w1;
        if (t >= 1) acc += p[-1*DI]*w2;
        acc += p[0]*w3;
    }
    float v = siluf(acc);
    xc[idx] = v;
    xcb[idx] = (__bf16)v;
}

// -------- scan pass 1: per-chunk (P_end, H_end) with h0 = 0 ----------
__global__ __launch_bounds__(256) void scan_p1(
    const float* __restrict__ dt, const float* __restrict__ xc,
    const float* __restrict__ dbl, const float* __restrict__ A_log,
    float* __restrict__ Pe, float* __restrict__ He)
{
    int wid = (blockIdx.x * 256 + threadIdx.x) >> 6;
    int lane = threadIdx.x & 63;
    int c = wid & (NC - 1);
    int d = (wid >> 4) & (DI - 1);
    int b = wid >> 13;
    float An = -__expf(A_log[d * NST + lane]);   // natural-log A
    size_t row0 = (size_t)b * LSEQ + (size_t)c * CL;
    float dtv = dt[(row0 + lane) * DI + d];
    float uv  = xc[(row0 + lane) * DI + d];
    float duv = dtv * uv;
    const float* bp = dbl + row0 * 144 + 16 + lane;
    float P = 1.f, H = 0.f;
    float Bv[8], Bn[8];
    #pragma unroll
    for (int q = 0; q < 8; ++q) Bv[q] = bp[q * 144];
    for (int t0 = 0; t0 < CL; t0 += 8) {
        if (t0 + 8 < CL) {
            #pragma unroll
            for (int q = 0; q < 8; ++q) Bn[q] = bp[(t0 + 8 + q) * 144];
        }
        #pragma unroll
        for (int q = 0; q < 8; ++q) {
            int t = t0 + q;
            float dts = rlane(dtv, t);
            float dus = rlane(duv, t);
            float dA = __expf(dts * An);
            P *= dA;
            H = fmaf(dA, H, dus * Bv[q]);
        }
        #pragma unroll
        for (int q = 0; q < 8; ++q) Bv[q] = Bn[q];
    }
    size_t o = (size_t)wid * 64 + lane;
    Pe[o] = P;
    He[o] = H;
}

// -------- scan pass 2: recombine carries, recompute, emit bf16 yT ----
__global__ __launch_bounds__(256) void scan_p2(
    const float* __restrict__ dt, const float* __restrict__ xc,
    const float* __restrict__ dbl, const float* __restrict__ z,
    const float* __restrict__ A_log, const float* __restrict__ Dp,
    const float* __restrict__ Pe, const float* __restrict__ He,
    __bf16* __restrict__ yT)
{
    int wid = (blockIdx.x * 256 + threadIdx.x) >> 6;
    int lane = threadIdx.x & 63;
    int c = wid & (NC - 1);
    int d = (wid >> 4) & (DI - 1);
    int b = wid >> 13;
    float h = 0.f;
    int base = (b << 13) + (d << 4);
    for (int j = 0; j < c; ++j) {
        size_t o = (size_t)(base + j) * 64 + lane;
        h = fmaf(Pe[o], h, He[o]);
    }
    float An = -__expf(A_log[d * NST + lane]);
    size_t row0 = (size_t)b * LSEQ + (size_t)c * CL;
    float dtv = dt[(row0 + lane) * DI + d];
    float uv  = xc[(row0 + lane) * DI + d];
    float zv  = z[(row0 + lane) * DI + d];
    float duv = dtv * uv;
    const float* bp = dbl + row0 * 144 + 16 + lane;
    const float* cp = dbl + row0 * 144 + 80 + lane;
    float Bv[8], Cv[8], Bn[8], Cn[8];
    #pragma unroll
    for (int q = 0; q < 8; ++q) { Bv[q] = bp[q * 144]; Cv[q] = cp[q * 144]; }
    float yv = 0.f;
    for (int t0 = 0; t0 < CL; t0 += 8) {
        if (t0 + 8 < CL) {
            #pragma unroll
            for (int q = 0; q < 8; ++q) {
                Bn[q] = bp[(t0 + 8 + q) * 144];
                Cn[q] = cp[(t0 + 8 + q) * 144];
            }
        }
        #pragma unroll
        for (int q = 0; q < 8; ++q) {
            int t = t0 + q;
            float dts = rlane(dtv, t);
            float dus = rlane(duv, t);
            float dA = __expf(dts * An);
            h = fmaf(dA, h, dus * Bv[q]);
            float s = h * Cv[q];
            s = wave_sum63(s);
            float tot = rlane(s, 63);
            if (lane == t) yv = tot;
        }
        #pragma unroll
        for (int q = 0; q < 8; ++q) { Bv[q] = Bn[q]; Cv[q] = Cn[q]; }
    }
    float y = (yv + uv * Dp[d]) * siluf(zv);
    yT[(size_t)d * ROWS + row0 + lane] = (__bf16)y;
}

// -------- bf16 transpose: in[512][4096] -> out[4096][512] ------------
__global__ __launch_bounds__(256) void transpose_bf(
    const u16* __restrict__ in, u16* __restrict__ out)
{
    __shared__ u16 tile[64][72];
    int r = threadIdx.x >> 2;
    int c0 = (threadIdx.x & 3) * 16;
    const u16* ip = in + (size_t)(blockIdx.y*64 + r) * 4096 + blockIdx.x*64 + c0;
    *(u16x8*)&tile[r][c0]     = *(const u16x8*)(ip);
    *(u16x8*)&tile[r][c0 + 8] = *(const u16x8*)(ip + 8);
    __syncthreads();
    u16* op = out + (size_t)(blockIdx.x*64 + r) * 512 + blockIdx.y*64 + c0;
    u16x8 v0, v1;
    #pragma unroll
    for (int i = 0; i < 8; ++i) { v0[i] = tile[c0+i][r]; v1[i] = tile[c0+8+i][r]; }
    *(u16x8*)(op)     = v0;
    *(u16x8*)(op + 8) = v1;
}

extern "C" void kernel_launch(void* const* d_in, const int* in_sizes, int n_in,
                              void* d_out, int out_size, void* d_ws, size_t ws_size,
                              hipStream_t stream)
{
    const float* x      = (const float*)d_in[0];
    const float* ln_g   = (const float*)d_in[1];
    const float* ln_b   = (const float*)d_in[2];
    const float* in_w   = (const float*)d_in[3];
    const float* conv_w = (const float*)d_in[4];
    const float* conv_b = (const float*)d_in[5];
    const float* xp_w   = (const float*)d_in[6];
    const float* dt_w   = (const float*)d_in[7];
    const float* dt_b   = (const float*)d_in[8];
    const float* A_log  = (const float*)d_in[9];
    const float* Dp     = (const float*)d_in[10];
    const float* out_w  = (const float*)d_in[11];
    float* out = (float*)d_out;

    char* ws = (char*)d_ws;
    const size_t MB = 1u << 20;
    float*  xm   = (float*)(ws + 0*MB);    // region A: xm then Pe
    float*  Pe   = (float*)(ws + 0*MB);
    float*  dtb  = (float*)(ws + 8*MB);
    float*  zb   = (float*)(ws + 16*MB);
    float*  xcb  = (float*)(ws + 24*MB);
    float*  He   = (float*)(ws + 32*MB);
    float*  dblb = (float*)(ws + 40*MB);   // 2.25 MB
    __bf16* xnb  = (__bf16*)(ws + 43*MB);  // region G: xn_bf then yT_bf
    __bf16* yTb  = (__bf16*)(ws + 43*MB);
    __bf16* xcbf = (__bf16*)(ws + 45*MB);  // region H: xc_bf then y_bf
    __bf16* ybf  = (__bf16*)(ws + 45*MB);
    __bf16* w_in  = (__bf16*)(ws + 49*MB);           // 2*1024*256
    __bf16* w_xp  = (__bf16*)(ws + 50*MB);           // 2*144*512
    __bf16* w_out = (__bf16*)(ws + 50*MB + 512*1024);// 2*256*512

    // one-time weight converts (both layers)
    f2bf<<<512, 256, 0, stream>>>(in_w,  w_in,  2*1024*DM);
    f2bf<<<144, 256, 0, stream>>>(xp_w,  w_xp,  2*144*DI);
    f2bf<<<256, 256, 0, stream>>>(out_w, w_out, 2*DM*DI);

    for (int l = 0; l < 2; ++l) {
        const float* xin = (l == 0) ? x : out;
        ln_kernel<<<ROWS/4, 256, 0, stream>>>(xin, ln_g + l*DM, ln_b + l*DM, xnb);
        // in_proj: [4096,256]bf16 @ [1024,256]^T -> split xm | z (fp32)
        gemm_mfma<DM><<<dim3(1024/64, ROWS/128), 256, 0, stream>>>(
            xnb, w_in + (size_t)l*1024*DM, xm, zb, nullptr, 1024, 1);
        conv_silu_kernel<<<(ROWS*DI)/256, 256, 0, stream>>>(
            xm, conv_w + (size_t)l*DI*4, conv_b + (size_t)l*DI, xcb, xcbf);
        // x_proj: [4096,512]bf16 @ [144,512]^T -> dbl fp32
        gemm_mfma<DI><<<dim3(3, ROWS/128), 256, 0, stream>>>(
            xcbf, w_xp + (size_t)l*144*DI, dblb, nullptr, nullptr, 144, 0);
        // dt: [4096,16] @ [512,16]^T + bias -> softplus (fp32)
        gemm_tn<<<dim3(DI/64, ROWS/64), 256, 0, stream>>>(
            dblb, 144, dt_w + (size_t)l*DI*16, dtb, dt_b + (size_t)l*DI,
            ROWS, DI, 16);
        // chunked scan
        scan_p1<<<(BB*DI*NC)/4, 256, 0, stream>>>(
            dtb, xcb, dblb, A_log + (size_t)l*DI*NST, Pe, He);
        scan_p2<<<(BB*DI*NC)/4, 256, 0, stream>>>(
            dtb, xcb, dblb, zb, A_log + (size_t)l*DI*NST, Dp + (size_t)l*DI,
            Pe, He, yTb);
        transpose_bf<<<dim3(ROWS/64, DI/64), 256, 0, stream>>>(
            (const u16*)yTb, (u16*)ybf);
        // out_proj + residual: [4096,512]bf16 @ [256,512]^T + xin -> out
        gemm_mfma<DI><<<dim3(DM/64, ROWS/128), 256, 0, stream>>>(
            ybf, w_out + (size_t)l*DM*DI, out, nullptr, xin, DM, 2);
    }
}

// Round 5
// 432.008 us; speedup vs baseline: 2.3907x; 1.0357x over previous
//
#include <hip/hip_runtime.h>
#include <math.h>

#define DI 512
#define DM 256
#define LSEQ 1024
#define BB 4
#define NST 64
#define ROWS (BB*LSEQ)   // 4096
#define NC 16            // chunks per sequence
#define CL 64            // chunk length

typedef __bf16 bf16x8 __attribute__((ext_vector_type(8)));
typedef __bf16 bf16x4 __attribute__((ext_vector_type(4)));
typedef float f32x4 __attribute__((ext_vector_type(4)));
typedef unsigned short u16;
typedef u16 u16x8 __attribute__((ext_vector_type(8)));

__device__ __forceinline__ float siluf(float x) { return x / (1.f + __expf(-x)); }
__device__ __forceinline__ float softplusf(float x) { return (x > 20.f) ? x : log1pf(__expf(x)); }
__device__ __forceinline__ float rlane(float v, int l) {
    return __int_as_float(__builtin_amdgcn_readlane(__float_as_int(v), l));
}
__device__ __forceinline__ unsigned pack_bf16(float lo, float hi) {
    unsigned r;
    asm("v_cvt_pk_bf16_f32 %0, %1, %2" : "=v"(r) : "v"(lo), "v"(hi));
    return r;
}

// pairing-tree reduction: sums s[0..7] (each across all 64 lanes).
// Result: lane L holds total of s[(L>>3)&7].
__device__ __forceinline__ float tree8(const float (&s)[8], int lane) {
    const bool b5 = (lane & 32) != 0;
    const bool b4 = (lane & 16) != 0;
    const bool b3 = (lane & 8) != 0;
    float r[4];
    #pragma unroll
    for (int i = 0; i < 4; ++i) {
        float u = b5 ? s[i+4] : s[i];
        float w = b5 ? s[i]   : s[i+4];
        r[i] = u + __shfl_xor(w, 32, 64);
    }
    float q[2];
    #pragma unroll
    for (int i = 0; i < 2; ++i) {
        float u = b4 ? r[i+2] : r[i];
        float w = b4 ? r[i]   : r[i+2];
        q[i] = u + __shfl_xor(w, 16, 64);
    }
    float u = b3 ? q[1] : q[0];
    float w = b3 ? q[0] : q[1];
    float p = u + __shfl_xor(w, 8, 64);
    p += __shfl_xor(p, 4, 64);
    p += __shfl_xor(p, 2, 64);
    p += __shfl_xor(p, 1, 64);
    return p;
}

// ---------------- float -> bf16 convert (weights) -------------------
__global__ __launch_bounds__(256) void f2bf(
    const float* __restrict__ in, __bf16* __restrict__ out, int n)
{
    int i = (blockIdx.x * 256 + threadIdx.x) * 4;
    if (i >= n) return;
    float4 v = *(const float4*)(in + i);
    bf16x4 o;
    o[0] = (__bf16)v.x; o[1] = (__bf16)v.y; o[2] = (__bf16)v.z; o[3] = (__bf16)v.w;
    *(bf16x4*)(out + i) = o;
}

// ---------------- LayerNorm: one wave per row of 256, bf16 out ------
__global__ __launch_bounds__(256) void ln_kernel(
    const float* __restrict__ x, const float* __restrict__ g,
    const float* __restrict__ b, __bf16* __restrict__ xn)
{
    int lane = threadIdx.x & 63;
    int row = blockIdx.x * 4 + (threadIdx.x >> 6);
    const float4* xr = (const float4*)(x + (size_t)row * DM);
    float4 v = xr[lane];
    float s = v.x + v.y + v.z + v.w;
    #pragma unroll
    for (int o = 32; o; o >>= 1) s += __shfl_xor(s, o, 64);
    float mu = s * (1.f / DM);
    float dx = v.x - mu, dy = v.y - mu, dz = v.z - mu, dw = v.w - mu;
    float q = dx*dx + dy*dy + dz*dz + dw*dw;
    #pragma unroll
    for (int o = 32; o; o >>= 1) q += __shfl_xor(q, o, 64);
    float inv = rsqrtf(q * (1.f / DM) + 1e-5f);
    float4 gv = ((const float4*)g)[lane];
    float4 bv = ((const float4*)b)[lane];
    bf16x4 o4;
    o4[0] = (__bf16)(dx * inv * gv.x + bv.x);
    o4[1] = (__bf16)(dy * inv * gv.y + bv.y);
    o4[2] = (__bf16)(dz * inv * gv.z + bv.z);
    o4[3] = (__bf16)(dw * inv * gv.w + bv.w);
    *(bf16x4*)(xn + (size_t)row * DM + lane * 4) = o4;
}

// ------------- bf16 MFMA GEMM: C[M,N] = A[M,K] @ W[N,K]^T -----------
template<int KK>
__global__ __launch_bounds__(256) void gemm_mfma(
    const __bf16* __restrict__ A, const __bf16* __restrict__ W,
    float* __restrict__ C, float* __restrict__ C2,
    const float* __restrict__ res, int N, int mode)
{
    int wid = threadIdx.x >> 6, lane = threadIdx.x & 63;
    int wr = wid >> 1, wc = wid & 1;
    int bm = blockIdx.y * 128, bn = blockIdx.x * 64;
    int l15 = lane & 15, lk = (lane >> 4) * 8;
    const __bf16* Ap = A + (size_t)(bm + wr*64 + l15) * KK + lk;
    int wrow0 = bn + wc*32 + l15;
    int wrow1 = wrow0 + 16;
    if (wrow0 > N-1) wrow0 = N-1;
    if (wrow1 > N-1) wrow1 = N-1;
    const __bf16* Wp0 = W + (size_t)wrow0 * KK + lk;
    const __bf16* Wp1 = W + (size_t)wrow1 * KK + lk;
    f32x4 acc[4][2] = {};
    #pragma unroll 4
    for (int k0 = 0; k0 < KK; k0 += 32) {
        bf16x8 b0 = *(const bf16x8*)(Wp0 + k0);
        bf16x8 b1 = *(const bf16x8*)(Wp1 + k0);
        #pragma unroll
        for (int m = 0; m < 4; ++m) {
            bf16x8 a = *(const bf16x8*)(Ap + (size_t)m*16*KK + k0);
            acc[m][0] = __builtin_amdgcn_mfma_f32_16x16x32_bf16(a, b0, acc[m][0], 0, 0, 0);
            acc[m][1] = __builtin_amdgcn_mfma_f32_16x16x32_bf16(a, b1, acc[m][1], 0, 0, 0);
        }
    }
    int r4 = (lane >> 4) * 4;
    #pragma unroll
    for (int m = 0; m < 4; ++m) {
        int row = bm + wr*64 + m*16 + r4;
        #pragma unroll
        for (int n = 0; n < 2; ++n) {
            int col = bn + wc*32 + n*16 + l15;
            #pragma unroll
            for (int r = 0; r < 4; ++r) {
                float v = acc[m][n][r];
                int rr = row + r;
                if (mode == 0) {
                    if (col < N) C[(size_t)rr * N + col] = v;
                } else if (mode == 1) {
                    if (col < 512) C[(size_t)rr * 512 + col] = v;
                    else           C2[(size_t)rr * 512 + col - 512] = v;
                } else {
                    C[(size_t)rr * N + col] = v + res[(size_t)rr * N + col];
                }
            }
        }
    }
}

// -------- fp32 tiled GEMM (dt projection only, K=16) ----------------
__global__ __launch_bounds__(256) void gemm_tn(
    const float* __restrict__ A, int lda,
    const float* __restrict__ W,
    float* __restrict__ C, const float* __restrict__ aux,
    int M, int N, int K)
{
    __shared__ float As[16][68];
    __shared__ float Ws[16][68];
    const int bm = blockIdx.y * 64;
    const int bn = blockIdx.x * 64;
    const int tid = threadIdx.x;
    const int tx = tid & 15;
    const int ty = tid >> 4;
    const int lr = tid >> 2;
    const int lc = (tid & 3) << 2;
    float acc[4][4] = {};

    for (int k0 = 0; k0 < K; k0 += 16) {
        float4 av = *(const float4*)(A + (size_t)(bm + lr) * lda + k0 + lc);
        float4 wv = *(const float4*)(W + (size_t)(bn + lr) * K + k0 + lc);
        __syncthreads();
        As[lc+0][lr] = av.x; As[lc+1][lr] = av.y; As[lc+2][lr] = av.z; As[lc+3][lr] = av.w;
        Ws[lc+0][lr] = wv.x; Ws[lc+1][lr] = wv.y; Ws[lc+2][lr] = wv.z; Ws[lc+3][lr] = wv.w;
        __syncthreads();
        #pragma unroll
        for (int k = 0; k < 16; ++k) {
            float a[4], w[4];
            #pragma unroll
            for (int i = 0; i < 4; ++i) a[i] = As[k][ty*4 + i];
            #pragma unroll
            for (int j = 0; j < 4; ++j) w[j] = Ws[k][tx*4 + j];
            #pragma unroll
            for (int i = 0; i < 4; ++i)
                #pragma unroll
                for (int j = 0; j < 4; ++j)
                    acc[i][j] = fmaf(a[i], w[j], acc[i][j]);
        }
    }

    #pragma unroll
    for (int i = 0; i < 4; ++i) {
        int m = bm + ty*4 + i;
        #pragma unroll
        for (int j = 0; j < 4; ++j) {
            int n = bn + tx*4 + j;
            C[(size_t)m * N + n] = softplusf(acc[i][j] + aux[n]);
        }
    }
}

// ---------------- causal depthwise conv (k=4) + SiLU ----------------
__global__ __launch_bounds__(256) void conv_silu_kernel(
    const float* __restrict__ xm, const float* __restrict__ cw,
    const float* __restrict__ cb, float* __restrict__ xc,
    __bf16* __restrict__ xcb)
{
    int idx = blockIdx.x * 256 + threadIdx.x;
    int d = idx & (DI - 1);
    int row = idx >> 9;
    int t = row & (LSEQ - 1);
    float w0 = cw[d*4+0], w1 = cw[d*4+1], w2 = cw[d*4+2], w3 = cw[d*4+3];
    float acc = cb[d];
    const float* p = xm + (size_t)row * DI + d;
    if (t >= 3) {
        acc += p[-3*DI]*w0 + p[-2*DI]*w1 + p[-1*DI]*w2 + p[0]*w3;
    } else {
        if (t >= 2) acc += p[-2*DI]*w1;
        if (t >= 1) acc += p[-1*DI]*w2;
        acc += p[0]*w3;
    }
    float v = siluf(acc);
    xc[idx] = v;
    xcb[idx] = (__bf16)v;
}

// -------- fused chunked scan: block = (b,d), wave c = chunk c --------
// y[t] = y_local[t] + sum_n M[t,n]*h0[n],  M = cumP*C (bf16-packed in regs)
__global__ __launch_bounds__(1024) void scan_fused(
    const float* __restrict__ dt, const float* __restrict__ xc,
    const float* __restrict__ dbl, const float* __restrict__ z,
    const float* __restrict__ A_log, const float* __restrict__ Dp,
    __bf16* __restrict__ yT)
{
    __shared__ float Pa[NC][NST];
    __shared__ float Ha[NC][NST];
    __shared__ float Ys[NC][NST];
    const int c = threadIdx.x >> 6;        // chunk = wave id
    const int lane = threadIdx.x & 63;
    const int bd = blockIdx.x;
    const int d = bd & (DI - 1);
    const int b = bd >> 9;
    const float An = -__expf(A_log[d * NST + lane]);   // lane = n
    const size_t row0 = (size_t)b * LSEQ + (size_t)c * CL;
    // lane = t loads
    const float dtv = dt[(row0 + lane) * DI + d];
    const float uv  = xc[(row0 + lane) * DI + d];
    const float zv  = z[(row0 + lane) * DI + d];
    const float duv = dtv * uv;
    const float gD  = uv * Dp[d];
    const float wz  = siluf(zv);
    // lane = n streams
    const float* bp = dbl + row0 * 144 + 16 + lane;
    const float* cp = dbl + row0 * 144 + 80 + lane;

    float h = 0.f, cpow = 1.f;
    float yred[8];
    unsigned M2[32];
    float Bv[8], Cv[8];
    #pragma unroll
    for (int q = 0; q < 8; ++q) { Bv[q] = bp[q*144]; Cv[q] = cp[q*144]; }

    #pragma unroll
    for (int j = 0; j < 8; ++j) {
        float Bn[8], Cn[8];
        if (j < 7) {
            #pragma unroll
            for (int q = 0; q < 8; ++q) {
                Bn[q] = bp[(8*j + 8 + q) * 144];
                Cn[q] = cp[(8*j + 8 + q) * 144];
            }
        }
        float s[8], m[8];
        #pragma unroll
        for (int q = 0; q < 8; ++q) {
            const int t = 8*j + q;
            float dts = rlane(dtv, t);
            float dus = rlane(duv, t);
            float dA = __expf(dts * An);
            h = fmaf(dA, h, dus * Bv[q]);
            cpow *= dA;
            s[q] = h * Cv[q];
            m[q] = cpow * Cv[q];
        }
        #pragma unroll
        for (int q = 0; q < 4; ++q) M2[4*j + q] = pack_bf16(m[2*q], m[2*q+1]);
        yred[j] = tree8(s, lane);
        #pragma unroll
        for (int q = 0; q < 8; ++q) { Bv[q] = Bn[q]; Cv[q] = Cn[q]; }
    }

    // chunk carry exchange
    Pa[c][lane] = cpow;
    Ha[c][lane] = h;
    __syncthreads();
    float h0 = 0.f;
    for (int jj = 0; jj < c; ++jj)
        h0 = fmaf(Pa[jj][lane], h0, Ha[jj][lane]);

    // correction: yred[j] += sum_n M[t,n]*h0[n]
    #pragma unroll
    for (int j = 0; j < 8; ++j) {
        float s2[8];
        #pragma unroll
        for (int q = 0; q < 8; ++q) {
            unsigned bits = M2[4*j + (q >> 1)];
            float Mv = __uint_as_float((q & 1) ? (bits & 0xFFFF0000u) : (bits << 16));
            s2[q] = Mv * h0;
        }
        yred[j] += tree8(s2, lane);
    }

    // stage: lane L holds y[8j + (L>>3)]; route to lane = t via LDS
    if ((lane & 7) == 0) {
        #pragma unroll
        for (int j = 0; j < 8; ++j) Ys[c][8*j + (lane >> 3)] = yred[j];
    }
    __syncthreads();
    float y = (Ys[c][lane] + gD) * wz;
    yT[(size_t)d * ROWS + row0 + lane] = (__bf16)y;
}

// -------- bf16 transpose: in[512][4096] -> out[4096][512] ------------
__global__ __launch_bounds__(256) void transpose_bf(
    const u16* __restrict__ in, u16* __restrict__ out)
{
    __shared__ u16 tile[64][72];
    int r = threadIdx.x >> 2;
    int c0 = (threadIdx.x & 3) * 16;
    const u16* ip = in + (size_t)(blockIdx.y*64 + r) * 4096 + blockIdx.x*64 + c0;
    *(u16x8*)&tile[r][c0]     = *(const u16x8*)(ip);
    *(u16x8*)&tile[r][c0 + 8] = *(const u16x8*)(ip + 8);
    __syncthreads();
    u16* op = out + (size_t)(blockIdx.x*64 + r) * 512 + blockIdx.y*64 + c0;
    u16x8 v0, v1;
    #pragma unroll
    for (int i = 0; i < 8; ++i) { v0[i] = tile[c0+i][r]; v1[i] = tile[c0+8+i][r]; }
    *(u16x8*)(op)     = v0;
    *(u16x8*)(op + 8) = v1;
}

extern "C" void kernel_launch(void* const* d_in, const int* in_sizes, int n_in,
                              void* d_out, int out_size, void* d_ws, size_t ws_size,
                              hipStream_t stream)
{
    const float* x      = (const float*)d_in[0];
    const float* ln_g   = (const float*)d_in[1];
    const float* ln_b   = (const float*)d_in[2];
    const float* in_w   = (const float*)d_in[3];
    const float* conv_w = (const float*)d_in[4];
    const float* conv_b = (const float*)d_in[5];
    const float* xp_w   = (const float*)d_in[6];
    const float* dt_w   = (const float*)d_in[7];
    const float* dt_b   = (const float*)d_in[8];
    const float* A_log  = (const float*)d_in[9];
    const float* Dp     = (const float*)d_in[10];
    const float* out_w  = (const float*)d_in[11];
    float* out = (float*)d_out;

    char* ws = (char*)d_ws;
    const size_t MB = 1u << 20;
    float*  xm   = (float*)(ws + 0*MB);
    float*  dtb  = (float*)(ws + 8*MB);
    float*  zb   = (float*)(ws + 16*MB);
    float*  xcb  = (float*)(ws + 24*MB);
    float*  dblb = (float*)(ws + 40*MB);
    __bf16* xnb  = (__bf16*)(ws + 43*MB);
    __bf16* yTb  = (__bf16*)(ws + 43*MB);
    __bf16* xcbf = (__bf16*)(ws + 45*MB);
    __bf16* ybf  = (__bf16*)(ws + 45*MB);
    __bf16* w_in  = (__bf16*)(ws + 49*MB);
    __bf16* w_xp  = (__bf16*)(ws + 50*MB);
    __bf16* w_out = (__bf16*)(ws + 50*MB + 512*1024);

    f2bf<<<512, 256, 0, stream>>>(in_w,  w_in,  2*1024*DM);
    f2bf<<<144, 256, 0, stream>>>(xp_w,  w_xp,  2*144*DI);
    f2bf<<<256, 256, 0, stream>>>(out_w, w_out, 2*DM*DI);

    for (int l = 0; l < 2; ++l) {
        const float* xin = (l == 0) ? x : out;
        ln_kernel<<<ROWS/4, 256, 0, stream>>>(xin, ln_g + l*DM, ln_b + l*DM, xnb);
        gemm_mfma<DM><<<dim3(1024/64, ROWS/128), 256, 0, stream>>>(
            xnb, w_in + (size_t)l*1024*DM, xm, zb, nullptr, 1024, 1);
        conv_silu_kernel<<<(ROWS*DI)/256, 256, 0, stream>>>(
            xm, conv_w + (size_t)l*DI*4, conv_b + (size_t)l*DI, xcb, xcbf);
        gemm_mfma<DI><<<dim3(3, ROWS/128), 256, 0, stream>>>(
            xcbf, w_xp + (size_t)l*144*DI, dblb, nullptr, nullptr, 144, 0);
        gemm_tn<<<dim3(DI/64, ROWS/64), 256, 0, stream>>>(
            dblb, 144, dt_w + (size_t)l*DI*16, dtb, dt_b + (size_t)l*DI,
            ROWS, DI, 16);
        scan_fused<<<BB*DI, 1024, 0, stream>>>(
            dtb, xcb, dblb, zb, A_log + (size_t)l*DI*NST, Dp + (size_t)l*DI, yTb);
        transpose_bf<<<dim3(ROWS/64, DI/64), 256, 0, stream>>>(
            (const u16*)yTb, (u16*)ybf);
        gemm_mfma<DI><<<dim3(DM/64, ROWS/128), 256, 0, stream>>>(
            ybf, w_out + (size_t)l*DM*DI, out, nullptr, xin, DM, 2);
    }
}

// Round 6
// 356.273 us; speedup vs baseline: 2.8989x; 1.2126x over previous
//
#include <hip/hip_runtime.h>
#include <math.h>

#define DI 512
#define DM 256
#define LSEQ 1024
#define BB 4
#define NST 64
#define ROWS (BB*LSEQ)   // 4096
#define NC 16            // chunks per sequence
#define CL 64            // chunk length

typedef __bf16 bf16x8 __attribute__((ext_vector_type(8)));
typedef __bf16 bf16x4 __attribute__((ext_vector_type(4)));
typedef float f32x4 __attribute__((ext_vector_type(4)));
typedef unsigned short u16;
typedef u16 u16x8 __attribute__((ext_vector_type(8)));

__device__ __forceinline__ float siluf(float x) { return x / (1.f + __expf(-x)); }
__device__ __forceinline__ float softplusf(float x) { return (x > 20.f) ? x : log1pf(__expf(x)); }
__device__ __forceinline__ float rlane(float v, int l) {
    return __int_as_float(__builtin_amdgcn_readlane(__float_as_int(v), l));
}
__device__ __forceinline__ float fexp2(float x) {
#if __has_builtin(__builtin_amdgcn_exp2f)
    return __builtin_amdgcn_exp2f(x);
#else
    return __expf(x * 0.69314718056f);
#endif
}

// pairing-tree reduction: sums s[0..7] (each across all 64 lanes).
// Result: lane L holds total of s[L>>3].
__device__ __forceinline__ float tree8(const float (&s)[8], int lane) {
    const bool b5 = (lane & 32) != 0;
    const bool b4 = (lane & 16) != 0;
    const bool b3 = (lane & 8) != 0;
    float r[4];
    #pragma unroll
    for (int i = 0; i < 4; ++i) {
        float u = b5 ? s[i+4] : s[i];
        float w = b5 ? s[i]   : s[i+4];
        r[i] = u + __shfl_xor(w, 32, 64);
    }
    float q[2];
    #pragma unroll
    for (int i = 0; i < 2; ++i) {
        float u = b4 ? r[i+2] : r[i];
        float w = b4 ? r[i]   : r[i+2];
        q[i] = u + __shfl_xor(w, 16, 64);
    }
    float u = b3 ? q[1] : q[0];
    float w = b3 ? q[0] : q[1];
    float p = u + __shfl_xor(w, 8, 64);
    p += __shfl_xor(p, 4, 64);
    p += __shfl_xor(p, 2, 64);
    p += __shfl_xor(p, 1, 64);
    return p;
}

// ---------------- float -> bf16 convert (weights) -------------------
__global__ __launch_bounds__(256) void f2bf(
    const float* __restrict__ in, __bf16* __restrict__ out, int n)
{
    int i = (blockIdx.x * 256 + threadIdx.x) * 4;
    if (i >= n) return;
    float4 v = *(const float4*)(in + i);
    bf16x4 o;
    o[0] = (__bf16)v.x; o[1] = (__bf16)v.y; o[2] = (__bf16)v.z; o[3] = (__bf16)v.w;
    *(bf16x4*)(out + i) = o;
}

// ---------------- LayerNorm: one wave per row of 256, bf16 out ------
__global__ __launch_bounds__(256) void ln_kernel(
    const float* __restrict__ x, const float* __restrict__ g,
    const float* __restrict__ b, __bf16* __restrict__ xn)
{
    int lane = threadIdx.x & 63;
    int row = blockIdx.x * 4 + (threadIdx.x >> 6);
    const float4* xr = (const float4*)(x + (size_t)row * DM);
    float4 v = xr[lane];
    float s = v.x + v.y + v.z + v.w;
    #pragma unroll
    for (int o = 32; o; o >>= 1) s += __shfl_xor(s, o, 64);
    float mu = s * (1.f / DM);
    float dx = v.x - mu, dy = v.y - mu, dz = v.z - mu, dw = v.w - mu;
    float q = dx*dx + dy*dy + dz*dz + dw*dw;
    #pragma unroll
    for (int o = 32; o; o >>= 1) q += __shfl_xor(q, o, 64);
    float inv = rsqrtf(q * (1.f / DM) + 1e-5f);
    float4 gv = ((const float4*)g)[lane];
    float4 bv = ((const float4*)b)[lane];
    bf16x4 o4;
    o4[0] = (__bf16)(dx * inv * gv.x + bv.x);
    o4[1] = (__bf16)(dy * inv * gv.y + bv.y);
    o4[2] = (__bf16)(dz * inv * gv.z + bv.z);
    o4[3] = (__bf16)(dw * inv * gv.w + bv.w);
    *(bf16x4*)(xn + (size_t)row * DM + lane * 4) = o4;
}

// ------------- bf16 MFMA GEMM: C[M,N] = A[M,K] @ W[N,K]^T -----------
// mode 0: fp32 store (col guard, ldc=N)
// mode 1: split at 512 -> C fp32 (ld 512) | C2b bf16 (ld 512)
// mode 2: fp32 store + res add (ldc=N)
template<int KK>
__global__ __launch_bounds__(256) void gemm_mfma(
    const __bf16* __restrict__ A, const __bf16* __restrict__ W,
    float* __restrict__ C, __bf16* __restrict__ C2b,
    const float* __restrict__ res, int N, int mode)
{
    int wid = threadIdx.x >> 6, lane = threadIdx.x & 63;
    int wr = wid >> 1, wc = wid & 1;
    int bm = blockIdx.y * 128, bn = blockIdx.x * 64;
    int l15 = lane & 15, lk = (lane >> 4) * 8;
    const __bf16* Ap = A + (size_t)(bm + wr*64 + l15) * KK + lk;
    int wrow0 = bn + wc*32 + l15;
    int wrow1 = wrow0 + 16;
    if (wrow0 > N-1) wrow0 = N-1;
    if (wrow1 > N-1) wrow1 = N-1;
    const __bf16* Wp0 = W + (size_t)wrow0 * KK + lk;
    const __bf16* Wp1 = W + (size_t)wrow1 * KK + lk;
    f32x4 acc[4][2] = {};
    #pragma unroll 4
    for (int k0 = 0; k0 < KK; k0 += 32) {
        bf16x8 b0 = *(const bf16x8*)(Wp0 + k0);
        bf16x8 b1 = *(const bf16x8*)(Wp1 + k0);
        #pragma unroll
        for (int m = 0; m < 4; ++m) {
            bf16x8 a = *(const bf16x8*)(Ap + (size_t)m*16*KK + k0);
            acc[m][0] = __builtin_amdgcn_mfma_f32_16x16x32_bf16(a, b0, acc[m][0], 0, 0, 0);
            acc[m][1] = __builtin_amdgcn_mfma_f32_16x16x32_bf16(a, b1, acc[m][1], 0, 0, 0);
        }
    }
    int r4 = (lane >> 4) * 4;
    #pragma unroll
    for (int m = 0; m < 4; ++m) {
        int row = bm + wr*64 + m*16 + r4;
        #pragma unroll
        for (int n = 0; n < 2; ++n) {
            int col = bn + wc*32 + n*16 + l15;
            #pragma unroll
            for (int r = 0; r < 4; ++r) {
                float v = acc[m][n][r];
                int rr = row + r;
                if (mode == 0) {
                    if (col < N) C[(size_t)rr * N + col] = v;
                } else if (mode == 1) {
                    if (col < 512) C[(size_t)rr * 512 + col] = v;
                    else           C2b[(size_t)rr * 512 + col - 512] = (__bf16)v;
                } else {
                    C[(size_t)rr * N + col] = v + res[(size_t)rr * N + col];
                }
            }
        }
    }
}

// -------- fp32 tiled GEMM (dt projection, K=16) -> TRANSPOSED out ----
// writes CT[n][m] (ld ROWS), fused softplus(acc + bias[n])
__global__ __launch_bounds__(256) void gemm_dt(
    const float* __restrict__ A, int lda,
    const float* __restrict__ W,
    float* __restrict__ CT, const float* __restrict__ aux)
{
    __shared__ float As[16][68];
    __shared__ float Ws[16][68];
    const int bm = blockIdx.y * 64;
    const int bn = blockIdx.x * 64;
    const int tid = threadIdx.x;
    const int tx = tid & 15;
    const int ty = tid >> 4;
    const int lr = tid >> 2;
    const int lc = (tid & 3) << 2;
    float acc[4][4] = {};

    {
        float4 av = *(const float4*)(A + (size_t)(bm + lr) * lda + lc);
        float4 wv = *(const float4*)(W + (size_t)(bn + lr) * 16 + lc);
        As[lc+0][lr] = av.x; As[lc+1][lr] = av.y; As[lc+2][lr] = av.z; As[lc+3][lr] = av.w;
        Ws[lc+0][lr] = wv.x; Ws[lc+1][lr] = wv.y; Ws[lc+2][lr] = wv.z; Ws[lc+3][lr] = wv.w;
        __syncthreads();
        #pragma unroll
        for (int k = 0; k < 16; ++k) {
            float a[4], w[4];
            #pragma unroll
            for (int i = 0; i < 4; ++i) a[i] = As[k][ty*4 + i];
            #pragma unroll
            for (int j = 0; j < 4; ++j) w[j] = Ws[k][tx*4 + j];
            #pragma unroll
            for (int i = 0; i < 4; ++i)
                #pragma unroll
                for (int j = 0; j < 4; ++j)
                    acc[i][j] = fmaf(a[i], w[j], acc[i][j]);
        }
    }

    #pragma unroll
    for (int j = 0; j < 4; ++j) {
        int n = bn + tx*4 + j;
        float bia = aux[n];
        float4 v;
        v.x = softplusf(acc[0][j] + bia);
        v.y = softplusf(acc[1][j] + bia);
        v.z = softplusf(acc[2][j] + bia);
        v.w = softplusf(acc[3][j] + bia);
        *(float4*)(CT + (size_t)n * ROWS + bm + ty*4) = v;
    }
}

// ------- causal depthwise conv (k=4) + SiLU, bf16 out [row][d] ------
__global__ __launch_bounds__(256) void conv_silu_kernel(
    const float* __restrict__ xm, const float* __restrict__ cw,
    const float* __restrict__ cb, __bf16* __restrict__ xcb)
{
    int idx = blockIdx.x * 256 + threadIdx.x;
    int d = idx & (DI - 1);
    int row = idx >> 9;
    int t = row & (LSEQ - 1);
    float w0 = cw[d*4+0], w1 = cw[d*4+1], w2 = cw[d*4+2], w3 = cw[d*4+3];
    float acc = cb[d];
    const float* p = xm + (size_t)row * DI + d;
    if (t >= 3) {
        acc += p[-3*DI]*w0 + p[-2*DI]*w1 + p[-1*DI]*w2 + p[0]*w3;
    } else {
        if (t >= 2) acc += p[-2*DI]*w1;
        if (t >= 1) acc += p[-1*DI]*w2;
        acc += p[0]*w3;
    }
    xcb[idx] = (__bf16)siluf(acc);
}

// ----- bf16 transpose: in[ldo/?]... in (R x C) ld=ldi -> out ld=ldo --
// grid: (ldi/64, ldo/64); reads in[(by*64+r)*ldi + bx*64+c],
// writes out[(bx*64+r)*ldo + by*64+c]
__global__ __launch_bounds__(256) void transpose_bf(
    const u16* __restrict__ in, u16* __restrict__ out, int ldi, int ldo)
{
    __shared__ u16 tile[64][72];
    int r = threadIdx.x >> 2;
    int c0 = (threadIdx.x & 3) * 16;
    const u16* ip = in + (size_t)(blockIdx.y*64 + r) * ldi + blockIdx.x*64 + c0;
    *(u16x8*)&tile[r][c0]     = *(const u16x8*)(ip);
    *(u16x8*)&tile[r][c0 + 8] = *(const u16x8*)(ip + 8);
    __syncthreads();
    u16* op = out + (size_t)(blockIdx.x*64 + r) * ldo + blockIdx.y*64 + c0;
    u16x8 v0, v1;
    #pragma unroll
    for (int i = 0; i < 8; ++i) { v0[i] = tile[c0+i][r]; v1[i] = tile[c0+8+i][r]; }
    *(u16x8*)(op)     = v0;
    *(u16x8*)(op + 8) = v1;
}

// -------- scan pass 1: per-chunk (P_end, H_end), transposed in -------
__global__ __launch_bounds__(256) void scan_p1T(
    const float* __restrict__ dtT, const __bf16* __restrict__ xcT,
    const float* __restrict__ dbl, const float* __restrict__ A_log,
    float* __restrict__ Pe, float* __restrict__ He)
{
    int wid = (blockIdx.x * 256 + threadIdx.x) >> 6;
    int lane = threadIdx.x & 63;
    int c = wid & (NC - 1);
    int d = (wid >> 4) & (DI - 1);
    int b = wid >> 13;
    float An2 = -__expf(A_log[d * NST + lane]) * 1.44269504f;
    size_t row0 = (size_t)b * LSEQ + (size_t)c * CL;
    size_t tix = (size_t)d * ROWS + row0;
    float dtv = dtT[tix + lane];
    float uvf = (float)xcT[tix + lane];
    float duv = dtv * uvf;
    const float* bp = dbl + row0 * 144 + 16 + lane;
    float P = 1.f, H = 0.f;
    float Bv[8], Bn[8];
    #pragma unroll
    for (int q = 0; q < 8; ++q) Bv[q] = bp[q * 144];
    #pragma unroll
    for (int j = 0; j < 8; ++j) {
        if (j < 7) {
            #pragma unroll
            for (int q = 0; q < 8; ++q) Bn[q] = bp[(8*j + 8 + q) * 144];
        }
        #pragma unroll
        for (int q = 0; q < 8; ++q) {
            const int t = 8*j + q;
            float dA = fexp2(rlane(dtv, t) * An2);
            P *= dA;
            H = fmaf(dA, H, rlane(duv, t) * Bv[q]);
        }
        #pragma unroll
        for (int q = 0; q < 8; ++q) Bv[q] = Bn[q];
    }
    size_t o = (size_t)wid * 64 + lane;
    Pe[o] = P;
    He[o] = H;
}

// -------- carry: combine chunk (P,H) chains; h0[c] -> Pe slot c-1 ----
__global__ __launch_bounds__(256) void scan_carry(
    float* __restrict__ Pe, const float* __restrict__ He)
{
    int wid = (blockIdx.x * 256 + threadIdx.x) >> 6;   // (b,d)
    int lane = threadIdx.x & 63;
    size_t base = (size_t)wid * NC * 64 + lane;
    float p[15], q[15];
    #pragma unroll
    for (int j = 0; j < 15; ++j) {
        p[j] = Pe[base + (size_t)j * 64];
        q[j] = He[base + (size_t)j * 64];
    }
    float h = 0.f;
    #pragma unroll
    for (int j = 0; j < 15; ++j) {
        h = fmaf(p[j], h, q[j]);
        Pe[base + (size_t)j * 64] = h;
    }
}

// -------- scan pass 2: seeded single pass, emit bf16 yT --------------
__global__ __launch_bounds__(256) void scan_p2T(
    const float* __restrict__ dtT, const __bf16* __restrict__ xcT,
    const __bf16* __restrict__ zT, const float* __restrict__ dbl,
    const float* __restrict__ A_log, const float* __restrict__ Dp,
    const float* __restrict__ Pe, __bf16* __restrict__ yT)
{
    __shared__ float Ys[4][64];
    int wid = (blockIdx.x * 256 + threadIdx.x) >> 6;
    int w = threadIdx.x >> 6;
    int lane = threadIdx.x & 63;
    int c = wid & (NC - 1);
    int d = (wid >> 4) & (DI - 1);
    int b = wid >> 13;
    float An2 = -__expf(A_log[d * NST + lane]) * 1.44269504f;
    size_t row0 = (size_t)b * LSEQ + (size_t)c * CL;
    size_t tix = (size_t)d * ROWS + row0;
    float dtv = dtT[tix + lane];
    float uvf = (float)xcT[tix + lane];
    float zvf = (float)zT[tix + lane];
    float duv = dtv * uvf;
    float gD  = uvf * Dp[d];
    float wz  = siluf(zvf);
    float h = (c == 0) ? 0.f : Pe[(size_t)(wid - 1) * 64 + lane];
    const float* bp = dbl + row0 * 144 + 16 + lane;
    const float* cp = dbl + row0 * 144 + 80 + lane;
    float Bv[8], Cv[8], Bn[8], Cn[8];
    #pragma unroll
    for (int q = 0; q < 8; ++q) { Bv[q] = bp[q*144]; Cv[q] = cp[q*144]; }
    float yred[8];
    #pragma unroll
    for (int j = 0; j < 8; ++j) {
        if (j < 7) {
            #pragma unroll
            for (int q = 0; q < 8; ++q) {
                Bn[q] = bp[(8*j + 8 + q) * 144];
                Cn[q] = cp[(8*j + 8 + q) * 144];
            }
        }
        float s[8];
        #pragma unroll
        for (int q = 0; q < 8; ++q) {
            const int t = 8*j + q;
            float dA = fexp2(rlane(dtv, t) * An2);
            h = fmaf(dA, h, rlane(duv, t) * Bv[q]);
            s[q] = h * Cv[q];
        }
        yred[j] = tree8(s, lane);
        #pragma unroll
        for (int q = 0; q < 8; ++q) { Bv[q] = Bn[q]; Cv[q] = Cn[q]; }
    }
    if ((lane & 7) == 0) {
        #pragma unroll
        for (int j = 0; j < 8; ++j) Ys[w][8*j + (lane >> 3)] = yred[j];
    }
    float y = (Ys[w][lane] + gD) * wz;
    yT[tix + lane] = (__bf16)y;
}

extern "C" void kernel_launch(void* const* d_in, const int* in_sizes, int n_in,
                              void* d_out, int out_size, void* d_ws, size_t ws_size,
                              hipStream_t stream)
{
    const float* x      = (const float*)d_in[0];
    const float* ln_g   = (const float*)d_in[1];
    const float* ln_b   = (const float*)d_in[2];
    const float* in_w   = (const float*)d_in[3];
    const float* conv_w = (const float*)d_in[4];
    const float* conv_b = (const float*)d_in[5];
    const float* xp_w   = (const float*)d_in[6];
    const float* dt_w   = (const float*)d_in[7];
    const float* dt_b   = (const float*)d_in[8];
    const float* A_log  = (const float*)d_in[9];
    const float* Dp     = (const float*)d_in[10];
    const float* out_w  = (const float*)d_in[11];
    float* out = (float*)d_out;

    char* ws = (char*)d_ws;
    const size_t MB = 1u << 20;
    // region plan (47 MB total, lifetime-disjoint reuse):
    float*  xm   = (float*)(ws + 0*MB);    // conv input; dead after conv
    float*  Pe   = (float*)(ws + 0*MB);    //   then p1 P / carry h0
    float*  dtT  = (float*)(ws + 8*MB);    // dt transposed [512][4096] fp32
    __bf16* xcbf = (__bf16*)(ws + 16*MB);  // conv out [4096][512] bf16; dead after transpose
    __bf16* yTb  = (__bf16*)(ws + 16*MB);  //   then scan out [512][4096]
    __bf16* xcT  = (__bf16*)(ws + 20*MB);  // [512][4096]
    __bf16* zbf  = (__bf16*)(ws + 24*MB);  // in_proj z [4096][512]; dead after transpose
    __bf16* ybf  = (__bf16*)(ws + 24*MB);  //   then y re-transposed [4096][512]
    __bf16* zT   = (__bf16*)(ws + 28*MB);  // [512][4096]
    float*  He   = (float*)(ws + 32*MB);   // p1 H
    float*  dblb = (float*)(ws + 40*MB);   // 2.25 MB
    __bf16* xnb  = (__bf16*)(ws + 43*MB);  // LN out [4096][256] (2 MB)
    __bf16* w_in  = (__bf16*)(ws + 45*MB);             // 1 MB
    __bf16* w_xp  = (__bf16*)(ws + 46*MB);             // 0.29 MB
    __bf16* w_out = (__bf16*)(ws + 46*MB + 512*1024);  // 0.5 MB

    f2bf<<<512, 256, 0, stream>>>(in_w,  w_in,  2*1024*DM);
    f2bf<<<144, 256, 0, stream>>>(xp_w,  w_xp,  2*144*DI);
    f2bf<<<256, 256, 0, stream>>>(out_w, w_out, 2*DM*DI);

    for (int l = 0; l < 2; ++l) {
        const float* xin = (l == 0) ? x : out;
        ln_kernel<<<ROWS/4, 256, 0, stream>>>(xin, ln_g + l*DM, ln_b + l*DM, xnb);
        // in_proj -> xm fp32 | z bf16
        gemm_mfma<DM><<<dim3(1024/64, ROWS/128), 256, 0, stream>>>(
            xnb, w_in + (size_t)l*1024*DM, xm, zbf, nullptr, 1024, 1);
        conv_silu_kernel<<<(ROWS*DI)/256, 256, 0, stream>>>(
            xm, conv_w + (size_t)l*DI*4, conv_b + (size_t)l*DI, xcbf);
        // x_proj -> dbl fp32
        gemm_mfma<DI><<<dim3(3, ROWS/128), 256, 0, stream>>>(
            xcbf, w_xp + (size_t)l*144*DI, dblb, nullptr, nullptr, 144, 0);
        // transposes to [d][row]
        transpose_bf<<<dim3(DI/64, ROWS/64), 256, 0, stream>>>(
            (const u16*)xcbf, (u16*)xcT, DI, ROWS);
        transpose_bf<<<dim3(DI/64, ROWS/64), 256, 0, stream>>>(
            (const u16*)zbf, (u16*)zT, DI, ROWS);
        // dt projection, writes transposed fp32 + softplus
        gemm_dt<<<dim3(DI/64, ROWS/64), 256, 0, stream>>>(
            dblb, 144, dt_w + (size_t)l*DI*16, dtT, dt_b + (size_t)l*DI);
        // chunked scan: p1 -> carry -> p2
        scan_p1T<<<(BB*DI*NC)/4, 256, 0, stream>>>(
            dtT, xcT, dblb, A_log + (size_t)l*DI*NST, Pe, He);
        scan_carry<<<(BB*DI)/4, 256, 0, stream>>>(Pe, He);
        scan_p2T<<<(BB*DI*NC)/4, 256, 0, stream>>>(
            dtT, xcT, zT, dblb, A_log + (size_t)l*DI*NST, Dp + (size_t)l*DI,
            Pe, yTb);
        transpose_bf<<<dim3(ROWS/64, DI/64), 256, 0, stream>>>(
            (const u16*)yTb, (u16*)ybf, ROWS, DI);
        // out_proj + residual
        gemm_mfma<DI><<<dim3(DM/64, ROWS/128), 256, 0, stream>>>(
            ybf, w_out + (size_t)l*DM*DI, out, nullptr, xin, DM, 2);
    }
}

// Round 7
// 325.482 us; speedup vs baseline: 3.1731x; 1.0946x over previous
//
#include <hip/hip_runtime.h>
#include <math.h>

#define DI 512
#define DM 256
#define LSEQ 1024
#define BB 4
#define NST 64
#define ROWS (BB*LSEQ)   // 4096
#define NC 16            // chunks per sequence
#define CL 64            // chunk length

typedef __bf16 bf16x8 __attribute__((ext_vector_type(8)));
typedef __bf16 bf16x4 __attribute__((ext_vector_type(4)));
typedef float f32x4 __attribute__((ext_vector_type(4)));
typedef unsigned short u16;
typedef u16 u16x8 __attribute__((ext_vector_type(8)));

__device__ __forceinline__ float siluf(float x) { return x / (1.f + __expf(-x)); }
__device__ __forceinline__ float softplusf(float x) { return (x > 20.f) ? x : log1pf(__expf(x)); }
__device__ __forceinline__ float rlane(float v, int l) {
    return __int_as_float(__builtin_amdgcn_readlane(__float_as_int(v), l));
}
__device__ __forceinline__ float fexp2(float x) {
#if __has_builtin(__builtin_amdgcn_exp2f)
    return __builtin_amdgcn_exp2f(x);
#else
    return __expf(x * 0.69314718056f);
#endif
}

// pairing-tree reduction: sums s[0..7] (each across all 64 lanes).
// Result: lane L holds total of s[L>>3].
__device__ __forceinline__ float tree8(const float (&s)[8], int lane) {
    const bool b5 = (lane & 32) != 0;
    const bool b4 = (lane & 16) != 0;
    const bool b3 = (lane & 8) != 0;
    float r[4];
    #pragma unroll
    for (int i = 0; i < 4; ++i) {
        float u = b5 ? s[i+4] : s[i];
        float w = b5 ? s[i]   : s[i+4];
        r[i] = u + __shfl_xor(w, 32, 64);
    }
    float q[2];
    #pragma unroll
    for (int i = 0; i < 2; ++i) {
        float u = b4 ? r[i+2] : r[i];
        float w = b4 ? r[i]   : r[i+2];
        q[i] = u + __shfl_xor(w, 16, 64);
    }
    float u = b3 ? q[1] : q[0];
    float w = b3 ? q[0] : q[1];
    float p = u + __shfl_xor(w, 8, 64);
    p += __shfl_xor(p, 4, 64);
    p += __shfl_xor(p, 2, 64);
    p += __shfl_xor(p, 1, 64);
    return p;
}

// ---------------- float -> bf16 convert (weights) -------------------
__global__ __launch_bounds__(256) void f2bf(
    const float* __restrict__ in, __bf16* __restrict__ out, int n)
{
    int i = (blockIdx.x * 256 + threadIdx.x) * 4;
    if (i >= n) return;
    float4 v = *(const float4*)(in + i);
    bf16x4 o;
    o[0] = (__bf16)v.x; o[1] = (__bf16)v.y; o[2] = (__bf16)v.z; o[3] = (__bf16)v.w;
    *(bf16x4*)(out + i) = o;
}

// ---------------- LayerNorm: one wave per row of 256, bf16 out ------
__global__ __launch_bounds__(256) void ln_kernel(
    const float* __restrict__ x, const float* __restrict__ g,
    const float* __restrict__ b, __bf16* __restrict__ xn)
{
    int lane = threadIdx.x & 63;
    int row = blockIdx.x * 4 + (threadIdx.x >> 6);
    const float4* xr = (const float4*)(x + (size_t)row * DM);
    float4 v = xr[lane];
    float s = v.x + v.y + v.z + v.w;
    #pragma unroll
    for (int o = 32; o; o >>= 1) s += __shfl_xor(s, o, 64);
    float mu = s * (1.f / DM);
    float dx = v.x - mu, dy = v.y - mu, dz = v.z - mu, dw = v.w - mu;
    float q = dx*dx + dy*dy + dz*dz + dw*dw;
    #pragma unroll
    for (int o = 32; o; o >>= 1) q += __shfl_xor(q, o, 64);
    float inv = rsqrtf(q * (1.f / DM) + 1e-5f);
    float4 gv = ((const float4*)g)[lane];
    float4 bv = ((const float4*)b)[lane];
    bf16x4 o4;
    o4[0] = (__bf16)(dx * inv * gv.x + bv.x);
    o4[1] = (__bf16)(dy * inv * gv.y + bv.y);
    o4[2] = (__bf16)(dz * inv * gv.z + bv.z);
    o4[3] = (__bf16)(dw * inv * gv.w + bv.w);
    *(bf16x4*)(xn + (size_t)row * DM + lane * 4) = o4;
}

// ------------- bf16 MFMA GEMM: C[M,N] = A[M,K] @ W[N,K]^T -----------
// block 256 = 4 waves (2x2); tile 64(M) x 64(N); wave subtile 32x32.
// mode 0: fp32 store (col guard, ldc=N)
// mode 1: split at 512 -> C fp32 (ld 512) | C2b bf16 (ld 512)
// mode 2: fp32 store + res add (ldc=N)
template<int KK>
__global__ __launch_bounds__(256) void gemm_mfma(
    const __bf16* __restrict__ A, const __bf16* __restrict__ W,
    float* __restrict__ C, __bf16* __restrict__ C2b,
    const float* __restrict__ res, int N, int mode)
{
    int wid = threadIdx.x >> 6, lane = threadIdx.x & 63;
    int wr = wid >> 1, wc = wid & 1;
    int bm = blockIdx.y * 64, bn = blockIdx.x * 64;
    int l15 = lane & 15, lk = (lane >> 4) * 8;
    const __bf16* Ap = A + (size_t)(bm + wr*32 + l15) * KK + lk;
    int wrow0 = bn + wc*32 + l15;
    int wrow1 = wrow0 + 16;
    if (wrow0 > N-1) wrow0 = N-1;
    if (wrow1 > N-1) wrow1 = N-1;
    const __bf16* Wp0 = W + (size_t)wrow0 * KK + lk;
    const __bf16* Wp1 = W + (size_t)wrow1 * KK + lk;
    f32x4 acc[2][2] = {};
    #pragma unroll 4
    for (int k0 = 0; k0 < KK; k0 += 32) {
        bf16x8 b0 = *(const bf16x8*)(Wp0 + k0);
        bf16x8 b1 = *(const bf16x8*)(Wp1 + k0);
        #pragma unroll
        for (int m = 0; m < 2; ++m) {
            bf16x8 a = *(const bf16x8*)(Ap + (size_t)m*16*KK + k0);
            acc[m][0] = __builtin_amdgcn_mfma_f32_16x16x32_bf16(a, b0, acc[m][0], 0, 0, 0);
            acc[m][1] = __builtin_amdgcn_mfma_f32_16x16x32_bf16(a, b1, acc[m][1], 0, 0, 0);
        }
    }
    int r4 = (lane >> 4) * 4;
    #pragma unroll
    for (int m = 0; m < 2; ++m) {
        int row = bm + wr*32 + m*16 + r4;
        #pragma unroll
        for (int n = 0; n < 2; ++n) {
            int col = bn + wc*32 + n*16 + l15;
            #pragma unroll
            for (int r = 0; r < 4; ++r) {
                float v = acc[m][n][r];
                int rr = row + r;
                if (mode == 0) {
                    if (col < N) C[(size_t)rr * N + col] = v;
                } else if (mode == 1) {
                    if (col < 512) C[(size_t)rr * 512 + col] = v;
                    else           C2b[(size_t)rr * 512 + col - 512] = (__bf16)v;
                } else {
                    C[(size_t)rr * N + col] = v + res[(size_t)rr * N + col];
                }
            }
        }
    }
}

// -------- fp32 tiled GEMM (dt projection, K=16) -> TRANSPOSED out ----
// writes CT[n][m] (ld ROWS), fused softplus(acc + bias[n])
__global__ __launch_bounds__(256) void gemm_dt(
    const float* __restrict__ A, int lda,
    const float* __restrict__ W,
    float* __restrict__ CT, const float* __restrict__ aux)
{
    __shared__ float As[16][68];
    __shared__ float Ws[16][68];
    const int bm = blockIdx.y * 64;
    const int bn = blockIdx.x * 64;
    const int tid = threadIdx.x;
    const int tx = tid & 15;
    const int ty = tid >> 4;
    const int lr = tid >> 2;
    const int lc = (tid & 3) << 2;
    float acc[4][4] = {};

    {
        float4 av = *(const float4*)(A + (size_t)(bm + lr) * lda + lc);
        float4 wv = *(const float4*)(W + (size_t)(bn + lr) * 16 + lc);
        As[lc+0][lr] = av.x; As[lc+1][lr] = av.y; As[lc+2][lr] = av.z; As[lc+3][lr] = av.w;
        Ws[lc+0][lr] = wv.x; Ws[lc+1][lr] = wv.y; Ws[lc+2][lr] = wv.z; Ws[lc+3][lr] = wv.w;
        __syncthreads();
        #pragma unroll
        for (int k = 0; k < 16; ++k) {
            float a[4], w[4];
            #pragma unroll
            for (int i = 0; i < 4; ++i) a[i] = As[k][ty*4 + i];
            #pragma unroll
            for (int j = 0; j < 4; ++j) w[j] = Ws[k][tx*4 + j];
            #pragma unroll
            for (int i = 0; i < 4; ++i)
                #pragma unroll
                for (int j = 0; j < 4; ++j)
                    acc[i][j] = fmaf(a[i], w[j], acc[i][j]);
        }
    }

    #pragma unroll
    for (int j = 0; j < 4; ++j) {
        int n = bn + tx*4 + j;
        float bia = aux[n];
        float4 v;
        v.x = softplusf(acc[0][j] + bia);
        v.y = softplusf(acc[1][j] + bia);
        v.z = softplusf(acc[2][j] + bia);
        v.w = softplusf(acc[3][j] + bia);
        *(float4*)(CT + (size_t)n * ROWS + bm + ty*4) = v;
    }
}

// ------- causal depthwise conv (k=4) + SiLU, bf16 out [row][d] ------
__global__ __launch_bounds__(256) void conv_silu_kernel(
    const float* __restrict__ xm, const float* __restrict__ cw,
    const float* __restrict__ cb, __bf16* __restrict__ xcb)
{
    int idx = blockIdx.x * 256 + threadIdx.x;
    int d = idx & (DI - 1);
    int row = idx >> 9;
    int t = row & (LSEQ - 1);
    float w0 = cw[d*4+0], w1 = cw[d*4+1], w2 = cw[d*4+2], w3 = cw[d*4+3];
    float acc = cb[d];
    const float* p = xm + (size_t)row * DI + d;
    if (t >= 3) {
        acc += p[-3*DI]*w0 + p[-2*DI]*w1 + p[-1*DI]*w2 + p[0]*w3;
    } else {
        if (t >= 2) acc += p[-2*DI]*w1;
        if (t >= 1) acc += p[-1*DI]*w2;
        acc += p[0]*w3;
    }
    xcb[idx] = (__bf16)siluf(acc);
}

// ----- bf16 transpose tile 64x64: ld=ldi -> out ld=ldo --------------
__global__ __launch_bounds__(256) void transpose_bf(
    const u16* __restrict__ in, u16* __restrict__ out, int ldi, int ldo)
{
    __shared__ u16 tile[64][72];
    int r = threadIdx.x >> 2;
    int c0 = (threadIdx.x & 3) * 16;
    const u16* ip = in + (size_t)(blockIdx.y*64 + r) * ldi + blockIdx.x*64 + c0;
    *(u16x8*)&tile[r][c0]     = *(const u16x8*)(ip);
    *(u16x8*)&tile[r][c0 + 8] = *(const u16x8*)(ip + 8);
    __syncthreads();
    u16* op = out + (size_t)(blockIdx.x*64 + r) * ldo + blockIdx.y*64 + c0;
    u16x8 v0, v1;
    #pragma unroll
    for (int i = 0; i < 8; ++i) { v0[i] = tile[c0+i][r]; v1[i] = tile[c0+8+i][r]; }
    *(u16x8*)(op)     = v0;
    *(u16x8*)(op + 8) = v1;
}

// -------- scan pass 1: per-chunk (P_end, H_end), transposed in -------
__global__ __launch_bounds__(256) void scan_p1T(
    const float* __restrict__ dtT, const __bf16* __restrict__ xcT,
    const float* __restrict__ dbl, const float* __restrict__ A_log,
    float* __restrict__ Pe, float* __restrict__ He)
{
    int wid = (blockIdx.x * 256 + threadIdx.x) >> 6;
    int lane = threadIdx.x & 63;
    int c = wid & (NC - 1);
    int d = (wid >> 4) & (DI - 1);
    int b = wid >> 13;
    float An2 = -__expf(A_log[d * NST + lane]) * 1.44269504f;
    size_t row0 = (size_t)b * LSEQ + (size_t)c * CL;
    size_t tix = (size_t)d * ROWS + row0;
    float dtv = dtT[tix + lane];
    float uvf = (float)xcT[tix + lane];
    float duv = dtv * uvf;
    // P_end = exp2(An2 * sum(dt)) -- single exp instead of per-step mul
    float Sdt = dtv;
    #pragma unroll
    for (int o = 32; o; o >>= 1) Sdt += __shfl_xor(Sdt, o, 64);
    const float* bp = dbl + row0 * 144 + 16 + lane;
    float H = 0.f;
    #pragma unroll
    for (int j = 0; j < 8; ++j) {
        #pragma unroll
        for (int q = 0; q < 8; ++q) {
            const int t = 8*j + q;
            float dA = fexp2(rlane(dtv, t) * An2);
            H = fmaf(dA, H, rlane(duv, t) * bp[q * 144]);
        }
        bp += 8 * 144;
    }
    size_t o = (size_t)wid * 64 + lane;
    Pe[o] = fexp2(An2 * Sdt);
    He[o] = H;
}

// -------- carry: combine chunk (P,H) chains; h0[c] -> Pe slot c-1 ----
__global__ __launch_bounds__(256) void scan_carry(
    float* __restrict__ Pe, const float* __restrict__ He)
{
    int wid = (blockIdx.x * 256 + threadIdx.x) >> 6;   // (b,d)
    int lane = threadIdx.x & 63;
    size_t base = (size_t)wid * NC * 64 + lane;
    float p[15], q[15];
    #pragma unroll
    for (int j = 0; j < 15; ++j) {
        p[j] = Pe[base + (size_t)j * 64];
        q[j] = He[base + (size_t)j * 64];
    }
    float h = 0.f;
    #pragma unroll
    for (int j = 0; j < 15; ++j) {
        h = fmaf(p[j], h, q[j]);
        Pe[base + (size_t)j * 64] = h;
    }
}

// -------- scan pass 2: seeded single pass, emit bf16 yT --------------
__global__ __launch_bounds__(256) void scan_p2T(
    const float* __restrict__ dtT, const __bf16* __restrict__ xcT,
    const __bf16* __restrict__ zT, const float* __restrict__ dbl,
    const float* __restrict__ A_log, const float* __restrict__ Dp,
    const float* __restrict__ Pe, __bf16* __restrict__ yT)
{
    __shared__ float Ys[4][64];
    int wid = (blockIdx.x * 256 + threadIdx.x) >> 6;
    int w = threadIdx.x >> 6;
    int lane = threadIdx.x & 63;
    int c = wid & (NC - 1);
    int d = (wid >> 4) & (DI - 1);
    int b = wid >> 13;
    float An2 = -__expf(A_log[d * NST + lane]) * 1.44269504f;
    size_t row0 = (size_t)b * LSEQ + (size_t)c * CL;
    size_t tix = (size_t)d * ROWS + row0;
    float dtv = dtT[tix + lane];
    float uvf = (float)xcT[tix + lane];
    float zvf = (float)zT[tix + lane];
    float duv = dtv * uvf;
    float gD  = uvf * Dp[d];
    float wz  = siluf(zvf);
    float h = (c == 0) ? 0.f : Pe[(size_t)(wid - 1) * 64 + lane];
    const float* bp = dbl + row0 * 144 + 16 + lane;
    const float* cp = dbl + row0 * 144 + 80 + lane;
    float yred[8];
    #pragma unroll
    for (int j = 0; j < 8; ++j) {
        float s[8];
        #pragma unroll
        for (int q = 0; q < 8; ++q) {
            const int t = 8*j + q;
            float dA = fexp2(rlane(dtv, t) * An2);
            h = fmaf(dA, h, rlane(duv, t) * bp[q * 144]);
            s[q] = h * cp[q * 144];
        }
        yred[j] = tree8(s, lane);
        bp += 8 * 144;
        cp += 8 * 144;
    }
    if ((lane & 7) == 0) {
        #pragma unroll
        for (int j = 0; j < 8; ++j) Ys[w][8*j + (lane >> 3)] = yred[j];
    }
    float y = (Ys[w][lane] + gD) * wz;
    yT[tix + lane] = (__bf16)y;
}

extern "C" void kernel_launch(void* const* d_in, const int* in_sizes, int n_in,
                              void* d_out, int out_size, void* d_ws, size_t ws_size,
                              hipStream_t stream)
{
    const float* x      = (const float*)d_in[0];
    const float* ln_g   = (const float*)d_in[1];
    const float* ln_b   = (const float*)d_in[2];
    const float* in_w   = (const float*)d_in[3];
    const float* conv_w = (const float*)d_in[4];
    const float* conv_b = (const float*)d_in[5];
    const float* xp_w   = (const float*)d_in[6];
    const float* dt_w   = (const float*)d_in[7];
    const float* dt_b   = (const float*)d_in[8];
    const float* A_log  = (const float*)d_in[9];
    const float* Dp     = (const float*)d_in[10];
    const float* out_w  = (const float*)d_in[11];
    float* out = (float*)d_out;

    char* ws = (char*)d_ws;
    const size_t MB = 1u << 20;
    float*  xm   = (float*)(ws + 0*MB);    // conv input; dead after conv
    float*  Pe   = (float*)(ws + 0*MB);    //   then p1 P / carry h0
    float*  dtT  = (float*)(ws + 8*MB);    // dt transposed [512][4096] fp32
    __bf16* xcbf = (__bf16*)(ws + 16*MB);  // conv out [4096][512]; dead after transpose
    __bf16* yTb  = (__bf16*)(ws + 16*MB);  //   then scan out [512][4096]
    __bf16* xcT  = (__bf16*)(ws + 20*MB);  // [512][4096]
    __bf16* zbf  = (__bf16*)(ws + 24*MB);  // in_proj z; dead after transpose
    __bf16* ybf  = (__bf16*)(ws + 24*MB);  //   then y re-transposed [4096][512]
    __bf16* zT   = (__bf16*)(ws + 28*MB);  // [512][4096]
    float*  He   = (float*)(ws + 32*MB);   // p1 H
    float*  dblb = (float*)(ws + 40*MB);   // 2.25 MB
    __bf16* xnb  = (__bf16*)(ws + 43*MB);  // LN out (2 MB)
    __bf16* w_in  = (__bf16*)(ws + 45*MB);
    __bf16* w_xp  = (__bf16*)(ws + 46*MB);
    __bf16* w_out = (__bf16*)(ws + 46*MB + 512*1024);

    f2bf<<<512, 256, 0, stream>>>(in_w,  w_in,  2*1024*DM);
    f2bf<<<144, 256, 0, stream>>>(xp_w,  w_xp,  2*144*DI);
    f2bf<<<256, 256, 0, stream>>>(out_w, w_out, 2*DM*DI);

    for (int l = 0; l < 2; ++l) {
        const float* xin = (l == 0) ? x : out;
        ln_kernel<<<ROWS/4, 256, 0, stream>>>(xin, ln_g + l*DM, ln_b + l*DM, xnb);
        // in_proj -> xm fp32 | z bf16
        gemm_mfma<DM><<<dim3(1024/64, ROWS/64), 256, 0, stream>>>(
            xnb, w_in + (size_t)l*1024*DM, xm, zbf, nullptr, 1024, 1);
        conv_silu_kernel<<<(ROWS*DI)/256, 256, 0, stream>>>(
            xm, conv_w + (size_t)l*DI*4, conv_b + (size_t)l*DI, xcbf);
        // x_proj -> dbl fp32
        gemm_mfma<DI><<<dim3(3, ROWS/64), 256, 0, stream>>>(
            xcbf, w_xp + (size_t)l*144*DI, dblb, nullptr, nullptr, 144, 0);
        // transposes to [d][row]
        transpose_bf<<<dim3(DI/64, ROWS/64), 256, 0, stream>>>(
            (const u16*)xcbf, (u16*)xcT, DI, ROWS);
        transpose_bf<<<dim3(DI/64, ROWS/64), 256, 0, stream>>>(
            (const u16*)zbf, (u16*)zT, DI, ROWS);
        // dt projection, writes transposed fp32 + softplus
        gemm_dt<<<dim3(DI/64, ROWS/64), 256, 0, stream>>>(
            dblb, 144, dt_w + (size_t)l*DI*16, dtT, dt_b + (size_t)l*DI);
        // chunked scan: p1 -> carry -> p2
        scan_p1T<<<(BB*DI*NC)/4, 256, 0, stream>>>(
            dtT, xcT, dblb, A_log + (size_t)l*DI*NST, Pe, He);
        scan_carry<<<(BB*DI)/4, 256, 0, stream>>>(Pe, He);
        scan_p2T<<<(BB*DI*NC)/4, 256, 0, stream>>>(
            dtT, xcT, zT, dblb, A_log + (size_t)l*DI*NST, Dp + (size_t)l*DI,
            Pe, yTb);
        transpose_bf<<<dim3(ROWS/64, DI/64), 256, 0, stream>>>(
            (const u16*)yTb, (u16*)ybf, ROWS, DI);
        // out_proj + residual
        gemm_mfma<DI><<<dim3(DM/64, ROWS/64), 256, 0, stream>>>(
            ybf, w_out + (size_t)l*DM*DI, out, nullptr, xin, DM, 2);
    }
}

// Round 9
// 314.640 us; speedup vs baseline: 3.2825x; 1.0345x over previous
//
#include <hip/hip_runtime.h>
#include <math.h>

#define DI 512
#define DM 256
#define LSEQ 1024
#define BB 4
#define NST 64
#define ROWS (BB*LSEQ)   // 4096
#define NC 16            // chunks per sequence
#define CL 64            // chunk length

typedef __bf16 bf16x8 __attribute__((ext_vector_type(8)));
typedef __bf16 bf16x4 __attribute__((ext_vector_type(4)));
typedef float f32x4 __attribute__((ext_vector_type(4)));
typedef unsigned short u16;
typedef u16 u16x8 __attribute__((ext_vector_type(8)));
typedef int i32x2 __attribute__((ext_vector_type(2)));

__device__ __forceinline__ float siluf(float x) { return x / (1.f + __expf(-x)); }
__device__ __forceinline__ float softplusf(float x) { return (x > 20.f) ? x : log1pf(__expf(x)); }
__device__ __forceinline__ float rlane(float v, int l) {
    return __int_as_float(__builtin_amdgcn_readlane(__float_as_int(v), l));
}
__device__ __forceinline__ float fexp2(float x) {
#if __has_builtin(__builtin_amdgcn_exp2f)
    return __builtin_amdgcn_exp2f(x);
#else
    return __expf(x * 0.69314718056f);
#endif
}
template<int PAT>
__device__ __forceinline__ float fswz(float v) {
    return __int_as_float(__builtin_amdgcn_ds_swizzle(__float_as_int(v), PAT));
}

// pairing-tree reduction: sums s[0..7] (each across all 64 lanes).
// Result: lane L holds total of s[L>>3].
__device__ __forceinline__ float tree8(const float (&s)[8], int lane) {
    const bool b4 = (lane & 16) != 0;
    const bool b3 = (lane & 8) != 0;
    float r[4];
#if __has_builtin(__builtin_amdgcn_permlane32_swap)
    #pragma unroll
    for (int i = 0; i < 4; ++i) {
        i32x2 pr = __builtin_amdgcn_permlane32_swap(
            __float_as_int(s[i]), __float_as_int(s[i+4]), false, false);
        r[i] = __int_as_float(pr[0]) + __int_as_float(pr[1]);
    }
#else
    const bool b5 = (lane & 32) != 0;
    #pragma unroll
    for (int i = 0; i < 4; ++i) {
        float u = b5 ? s[i+4] : s[i];
        float w = b5 ? s[i]   : s[i+4];
        r[i] = u + __shfl_xor(w, 32, 64);
    }
#endif
    float q[2];
    #pragma unroll
    for (int i = 0; i < 2; ++i) {
        float u = b4 ? r[i+2] : r[i];
        float w = b4 ? r[i]   : r[i+2];
        q[i] = u + fswz<0x401F>(w);   // xor 16 (within 32-group)
    }
    float u = b3 ? q[1] : q[0];
    float w = b3 ? q[0] : q[1];
    float p = u + fswz<0x201F>(w);    // xor 8
    p += fswz<0x101F>(p);             // xor 4
    p += fswz<0x081F>(p);             // xor 2
    p += fswz<0x041F>(p);             // xor 1
    return p;
}

// ---------------- float -> bf16 convert (weights) -------------------
__global__ __launch_bounds__(256) void f2bf(
    const float* __restrict__ in, __bf16* __restrict__ out, int n)
{
    int i = (blockIdx.x * 256 + threadIdx.x) * 4;
    if (i >= n) return;
    float4 v = *(const float4*)(in + i);
    bf16x4 o;
    o[0] = (__bf16)v.x; o[1] = (__bf16)v.y; o[2] = (__bf16)v.z; o[3] = (__bf16)v.w;
    *(bf16x4*)(out + i) = o;
}

// ---------------- LayerNorm: one wave per row of 256, bf16 out ------
__global__ __launch_bounds__(256) void ln_kernel(
    const float* __restrict__ x, const float* __restrict__ g,
    const float* __restrict__ b, __bf16* __restrict__ xn)
{
    int lane = threadIdx.x & 63;
    int row = blockIdx.x * 4 + (threadIdx.x >> 6);
    const float4* xr = (const float4*)(x + (size_t)row * DM);
    float4 v = xr[lane];
    float s = v.x + v.y + v.z + v.w;
    #pragma unroll
    for (int o = 32; o; o >>= 1) s += __shfl_xor(s, o, 64);
    float mu = s * (1.f / DM);
    float dx = v.x - mu, dy = v.y - mu, dz = v.z - mu, dw = v.w - mu;
    float q = dx*dx + dy*dy + dz*dz + dw*dw;
    #pragma unroll
    for (int o = 32; o; o >>= 1) q += __shfl_xor(q, o, 64);
    float inv = rsqrtf(q * (1.f / DM) + 1e-5f);
    float4 gv = ((const float4*)g)[lane];
    float4 bv = ((const float4*)b)[lane];
    bf16x4 o4;
    o4[0] = (__bf16)(dx * inv * gv.x + bv.x);
    o4[1] = (__bf16)(dy * inv * gv.y + bv.y);
    o4[2] = (__bf16)(dz * inv * gv.z + bv.z);
    o4[3] = (__bf16)(dw * inv * gv.w + bv.w);
    *(bf16x4*)(xn + (size_t)row * DM + lane * 4) = o4;
}

// ------------- bf16 MFMA GEMM: C[M,N] = A[M,K] @ W[N,K]^T -----------
// block 256 = 4 waves (2x2); tile 64(M) x 64(N); wave subtile 32x32.
template<int KK>
__global__ __launch_bounds__(256) void gemm_mfma(
    const __bf16* __restrict__ A, const __bf16* __restrict__ W,
    float* __restrict__ C, __bf16* __restrict__ C2b,
    const float* __restrict__ res, int N, int mode)
{
    int wid = threadIdx.x >> 6, lane = threadIdx.x & 63;
    int wr = wid >> 1, wc = wid & 1;
    int bm = blockIdx.y * 64, bn = blockIdx.x * 64;
    int l15 = lane & 15, lk = (lane >> 4) * 8;
    const __bf16* Ap = A + (size_t)(bm + wr*32 + l15) * KK + lk;
    int wrow0 = bn + wc*32 + l15;
    int wrow1 = wrow0 + 16;
    if (wrow0 > N-1) wrow0 = N-1;
    if (wrow1 > N-1) wrow1 = N-1;
    const __bf16* Wp0 = W + (size_t)wrow0 * KK + lk;
    const __bf16* Wp1 = W + (size_t)wrow1 * KK + lk;
    f32x4 acc[2][2] = {};
    #pragma unroll 4
    for (int k0 = 0; k0 < KK; k0 += 32) {
        bf16x8 b0 = *(const bf16x8*)(Wp0 + k0);
        bf16x8 b1 = *(const bf16x8*)(Wp1 + k0);
        #pragma unroll
        for (int m = 0; m < 2; ++m) {
            bf16x8 a = *(const bf16x8*)(Ap + (size_t)m*16*KK + k0);
            acc[m][0] = __builtin_amdgcn_mfma_f32_16x16x32_bf16(a, b0, acc[m][0], 0, 0, 0);
            acc[m][1] = __builtin_amdgcn_mfma_f32_16x16x32_bf16(a, b1, acc[m][1], 0, 0, 0);
        }
    }
    int r4 = (lane >> 4) * 4;
    #pragma unroll
    for (int m = 0; m < 2; ++m) {
        int row = bm + wr*32 + m*16 + r4;
        #pragma unroll
        for (int n = 0; n < 2; ++n) {
            int col = bn + wc*32 + n*16 + l15;
            #pragma unroll
            for (int r = 0; r < 4; ++r) {
                float v = acc[m][n][r];
                int rr = row + r;
                if (mode == 0) {
                    if (col < N) C[(size_t)rr * N + col] = v;
                } else if (mode == 1) {
                    if (col < 512) C[(size_t)rr * 512 + col] = v;
                    else           C2b[(size_t)rr * 512 + col - 512] = (__bf16)v;
                } else {
                    C[(size_t)rr * N + col] = v + res[(size_t)rr * N + col];
                }
            }
        }
    }
}

// -------- fp32 tiled GEMM (dt projection, K=16) -> TRANSPOSED out ----
__global__ __launch_bounds__(256) void gemm_dt(
    const float* __restrict__ A, int lda,
    const float* __restrict__ W,
    float* __restrict__ CT, const float* __restrict__ aux)
{
    __shared__ float As[16][68];
    __shared__ float Ws[16][68];
    const int bm = blockIdx.y * 64;
    const int bn = blockIdx.x * 64;
    const int tid = threadIdx.x;
    const int tx = tid & 15;
    const int ty = tid >> 4;
    const int lr = tid >> 2;
    const int lc = (tid & 3) << 2;
    float acc[4][4] = {};
    {
        float4 av = *(const float4*)(A + (size_t)(bm + lr) * lda + lc);
        float4 wv = *(const float4*)(W + (size_t)(bn + lr) * 16 + lc);
        As[lc+0][lr] = av.x; As[lc+1][lr] = av.y; As[lc+2][lr] = av.z; As[lc+3][lr] = av.w;
        Ws[lc+0][lr] = wv.x; Ws[lc+1][lr] = wv.y; Ws[lc+2][lr] = wv.z; Ws[lc+3][lr] = wv.w;
        __syncthreads();
        #pragma unroll
        for (int k = 0; k < 16; ++k) {
            float a[4], w[4];
            #pragma unroll
            for (int i = 0; i < 4; ++i) a[i] = As[k][ty*4 + i];
            #pragma unroll
            for (int j = 0; j < 4; ++j) w[j] = Ws[k][tx*4 + j];
            #pragma unroll
            for (int i = 0; i < 4; ++i)
                #pragma unroll
                for (int j = 0; j < 4; ++j)
                    acc[i][j] = fmaf(a[i], w[j], acc[i][j]);
        }
    }
    #pragma unroll
    for (int j = 0; j < 4; ++j) {
        int n = bn + tx*4 + j;
        float bia = aux[n];
        float4 v;
        v.x = softplusf(acc[0][j] + bia);
        v.y = softplusf(acc[1][j] + bia);
        v.z = softplusf(acc[2][j] + bia);
        v.w = softplusf(acc[3][j] + bia);
        *(float4*)(CT + (size_t)n * ROWS + bm + ty*4) = v;
    }
}

// --- fused: conv(k=4)+SiLU with dual-layout out, plus z transpose ----
// block: 64 rows (t) x 64 d tile. outputs: xcb row-major bf16,
// xcT [512][4096], zT [512][4096].
__global__ __launch_bounds__(256) void conv_tr_kernel(
    const float* __restrict__ xm, const float* __restrict__ cw,
    const float* __restrict__ cb, const u16* __restrict__ zin,
    __bf16* __restrict__ xcb, u16* __restrict__ xcT, u16* __restrict__ zT)
{
    __shared__ float xs[67][66];
    __shared__ u16 Tc[64][72];
    __shared__ u16 Tz[64][72];
    const int tid = threadIdx.x;
    const int row0 = blockIdx.y * 64;
    const int d0 = blockIdx.x * 64;
    // stage xm rows row0-3 .. row0+63 (67 rows x 64 d)
    #pragma unroll
    for (int it = 0; it < 5; ++it) {
        int f4 = it * 256 + tid;
        if (f4 < 67 * 16) {
            int rr = f4 >> 4;
            int cc = (f4 & 15) * 4;
            int g = row0 - 3 + rr;
            float4 v = make_float4(0.f, 0.f, 0.f, 0.f);
            if (g >= 0 && (g >> 10) == (row0 >> 10))
                v = *(const float4*)(xm + (size_t)g * DI + d0 + cc);
            *(float4*)&xs[rr][cc] = v;
        }
    }
    const int r = tid >> 2;
    const int c0 = (tid & 3) * 16;
    // stage z tile
    {
        const u16* zp = zin + (size_t)(row0 + r) * DI + d0 + c0;
        *(u16x8*)&Tz[r][c0]     = *(const u16x8*)(zp);
        *(u16x8*)&Tz[r][c0 + 8] = *(const u16x8*)(zp + 8);
    }
    __syncthreads();
    // conv + silu: output row row0+r, d = d0+c0+j  (taps xs[r..r+3])
    {
        bf16x8 v0, v1;
        #pragma unroll
        for (int j = 0; j < 16; ++j) {
            int d = d0 + c0 + j;
            float acc = cb[d]
                + xs[r+0][c0+j] * cw[d*4+0]
                + xs[r+1][c0+j] * cw[d*4+1]
                + xs[r+2][c0+j] * cw[d*4+2]
                + xs[r+3][c0+j] * cw[d*4+3];
            __bf16 o = (__bf16)siluf(acc);
            if (j < 8) v0[j] = o; else v1[j-8] = o;
            Tc[r][c0+j] = *(const u16*)&o;
        }
        __bf16* op = xcb + (size_t)(row0 + r) * DI + d0 + c0;
        *(bf16x8*)(op)     = v0;
        *(bf16x8*)(op + 8) = v1;
    }
    __syncthreads();
    // transposed writes: out row = d0+r, cols = row0+c0..+15
    {
        u16x8 a0, a1, b0, b1;
        #pragma unroll
        for (int i = 0; i < 8; ++i) {
            a0[i] = Tc[c0+i][r];   a1[i] = Tc[c0+8+i][r];
            b0[i] = Tz[c0+i][r];   b1[i] = Tz[c0+8+i][r];
        }
        u16* oc = xcT + (size_t)(d0 + r) * ROWS + row0 + c0;
        u16* oz = zT  + (size_t)(d0 + r) * ROWS + row0 + c0;
        *(u16x8*)(oc)     = a0;
        *(u16x8*)(oc + 8) = a1;
        *(u16x8*)(oz)     = b0;
        *(u16x8*)(oz + 8) = b1;
    }
}

// ----- bf16 transpose tile 64x64: ld=ldi -> out ld=ldo (y only) -----
__global__ __launch_bounds__(256) void transpose_bf(
    const u16* __restrict__ in, u16* __restrict__ out, int ldi, int ldo)
{
    __shared__ u16 tile[64][72];
    int r = threadIdx.x >> 2;
    int c0 = (threadIdx.x & 3) * 16;
    const u16* ip = in + (size_t)(blockIdx.y*64 + r) * ldi + blockIdx.x*64 + c0;
    *(u16x8*)&tile[r][c0]     = *(const u16x8*)(ip);
    *(u16x8*)&tile[r][c0 + 8] = *(const u16x8*)(ip + 8);
    __syncthreads();
    u16* op = out + (size_t)(blockIdx.x*64 + r) * ldo + blockIdx.y*64 + c0;
    u16x8 v0, v1;
    #pragma unroll
    for (int i = 0; i < 8; ++i) { v0[i] = tile[c0+i][r]; v1[i] = tile[c0+8+i][r]; }
    *(u16x8*)(op)     = v0;
    *(u16x8*)(op + 8) = v1;
}

// -------- scan pass 1: per-chunk (P_end, H_end), transposed in -------
__global__ __launch_bounds__(256) void scan_p1T(
    const float* __restrict__ dtT, const __bf16* __restrict__ xcT,
    const float* __restrict__ dbl, const float* __restrict__ A_log,
    float* __restrict__ Pe, float* __restrict__ He)
{
    int wid = (blockIdx.x * 256 + threadIdx.x) >> 6;
    int lane = threadIdx.x & 63;
    int c = wid & (NC - 1);
    int d = (wid >> 4) & (DI - 1);
    int b = wid >> 13;
    float An2 = -__expf(A_log[d * NST + lane]) * 1.44269504f;
    size_t row0 = (size_t)b * LSEQ + (size_t)c * CL;
    size_t tix = (size_t)d * ROWS + row0;
    float dtv = dtT[tix + lane];
    float uvf = (float)xcT[tix + lane];
    float duv = dtv * uvf;
    float Sdt = dtv;
    #pragma unroll
    for (int o = 32; o; o >>= 1) Sdt += __shfl_xor(Sdt, o, 64);
    const float* bp = dbl + row0 * 144 + 16 + lane;
    float H = 0.f;
    #pragma unroll
    for (int j = 0; j < 8; ++j) {
        #pragma unroll
        for (int q = 0; q < 8; ++q) {
            const int t = 8*j + q;
            float dA = fexp2(rlane(dtv, t) * An2);
            H = fmaf(dA, H, rlane(duv, t) * bp[q * 144]);
        }
        bp += 8 * 144;
    }
    size_t o = (size_t)wid * 64 + lane;
    Pe[o] = fexp2(An2 * Sdt);
    He[o] = H;
}

// -------- scan pass 2: inline carry + seeded pass, emit bf16 yT ------
__global__ __launch_bounds__(256) void scan_p2T(
    const float* __restrict__ dtT, const __bf16* __restrict__ xcT,
    const __bf16* __restrict__ zT, const float* __restrict__ dbl,
    const float* __restrict__ A_log, const float* __restrict__ Dp,
    const float* __restrict__ Pe, const float* __restrict__ He,
    __bf16* __restrict__ yT)
{
    __shared__ float Ys[4][64];
    int wid = (blockIdx.x * 256 + threadIdx.x) >> 6;
    int w = threadIdx.x >> 6;
    int lane = threadIdx.x & 63;
    int c = wid & (NC - 1);
    int d = (wid >> 4) & (DI - 1);
    int b = wid >> 13;
    float An2 = -__expf(A_log[d * NST + lane]) * 1.44269504f;
    size_t row0 = (size_t)b * LSEQ + (size_t)c * CL;
    size_t tix = (size_t)d * ROWS + row0;
    float dtv = dtT[tix + lane];
    float uvf = (float)xcT[tix + lane];
    float zvf = (float)zT[tix + lane];
    float duv = dtv * uvf;
    float gD  = uvf * Dp[d];
    float wz  = siluf(zvf);
    // inline carry: combine chunks 0..c-1 of this (b,d)
    float h = 0.f;
    {
        int cbase = wid - c;
        for (int j = 0; j < c; ++j) {
            size_t o = (size_t)(cbase + j) * 64 + lane;
            h = fmaf(Pe[o], h, He[o]);
        }
    }
    const float* bp = dbl + row0 * 144 + 16 + lane;
    const float* cp = dbl + row0 * 144 + 80 + lane;
    float yred[8];
    #pragma unroll
    for (int j = 0; j < 8; ++j) {
        float s[8];
        #pragma unroll
        for (int q = 0; q < 8; ++q) {
            const int t = 8*j + q;
            float dA = fexp2(rlane(dtv, t) * An2);
            h = fmaf(dA, h, rlane(duv, t) * bp[q * 144]);
            s[q] = h * cp[q * 144];
        }
        yred[j] = tree8(s, lane);
        bp += 8 * 144;
        cp += 8 * 144;
    }
    if ((lane & 7) == 0) {
        #pragma unroll
        for (int j = 0; j < 8; ++j) Ys[w][8*j + (lane >> 3)] = yred[j];
    }
    float y = (Ys[w][lane] + gD) * wz;
    yT[tix + lane] = (__bf16)y;
}

extern "C" void kernel_launch(void* const* d_in, const int* in_sizes, int n_in,
                              void* d_out, int out_size, void* d_ws, size_t ws_size,
                              hipStream_t stream)
{
    const float* x      = (const float*)d_in[0];
    const float* ln_g   = (const float*)d_in[1];
    const float* ln_b   = (const float*)d_in[2];
    const float* in_w   = (const float*)d_in[3];
    const float* conv_w = (const float*)d_in[4];
    const float* conv_b = (const float*)d_in[5];
    const float* xp_w   = (const float*)d_in[6];
    const float* dt_w   = (const float*)d_in[7];
    const float* dt_b   = (const float*)d_in[8];
    const float* A_log  = (const float*)d_in[9];
    const float* Dp     = (const float*)d_in[10];
    const float* out_w  = (const float*)d_in[11];
    float* out = (float*)d_out;

    char* ws = (char*)d_ws;
    const size_t MB = 1u << 20;
    float*  xm   = (float*)(ws + 0*MB);    // conv input; dead after conv
    float*  Pe   = (float*)(ws + 0*MB);    //   then p1 P
    float*  dtT  = (float*)(ws + 8*MB);    // [512][4096] fp32
    __bf16* xcbf = (__bf16*)(ws + 16*MB);  // conv out [4096][512]; dead after x_proj
    __bf16* yTb  = (__bf16*)(ws + 16*MB);  //   then scan out [512][4096]
    __bf16* xcT  = (__bf16*)(ws + 20*MB);  // [512][4096]
    __bf16* zbf  = (__bf16*)(ws + 24*MB);  // in_proj z; dead after conv_tr
    __bf16* ybf  = (__bf16*)(ws + 24*MB);  //   then y re-transposed [4096][512]
    __bf16* zT   = (__bf16*)(ws + 28*MB);  // [512][4096]
    float*  He   = (float*)(ws + 32*MB);   // p1 H
    float*  dblb = (float*)(ws + 40*MB);   // 2.25 MB
    __bf16* xnb  = (__bf16*)(ws + 43*MB);  // LN out (2 MB)
    __bf16* w_in  = (__bf16*)(ws + 45*MB);
    __bf16* w_xp  = (__bf16*)(ws + 46*MB);
    __bf16* w_out = (__bf16*)(ws + 46*MB + 512*1024);

    f2bf<<<512, 256, 0, stream>>>(in_w,  w_in,  2*1024*DM);
    f2bf<<<144, 256, 0, stream>>>(xp_w,  w_xp,  2*144*DI);
    f2bf<<<256, 256, 0, stream>>>(out_w, w_out, 2*DM*DI);

    for (int l = 0; l < 2; ++l) {
        const float* xin = (l == 0) ? x : out;
        ln_kernel<<<ROWS/4, 256, 0, stream>>>(xin, ln_g + l*DM, ln_b + l*DM, xnb);
        // in_proj -> xm fp32 | z bf16
        gemm_mfma<DM><<<dim3(1024/64, ROWS/64), 256, 0, stream>>>(
            xnb, w_in + (size_t)l*1024*DM, xm, zbf, nullptr, 1024, 1);
        // fused conv+silu (dual layout) + z transpose
        conv_tr_kernel<<<dim3(DI/64, ROWS/64), 256, 0, stream>>>(
            xm, conv_w + (size_t)l*DI*4, conv_b + (size_t)l*DI,
            (const u16*)zbf, xcbf, (u16*)xcT, (u16*)zT);
        // x_proj -> dbl fp32
        gemm_mfma<DI><<<dim3(3, ROWS/64), 256, 0, stream>>>(
            xcbf, w_xp + (size_t)l*144*DI, dblb, nullptr, nullptr, 144, 0);
        // dt projection, transposed fp32 out + softplus
        gemm_dt<<<dim3(DI/64, ROWS/64), 256, 0, stream>>>(
            dblb, 144, dt_w + (size_t)l*DI*16, dtT, dt_b + (size_t)l*DI);
        // chunked scan: p1 -> p2 (carry inlined)
        scan_p1T<<<(BB*DI*NC)/4, 256, 0, stream>>>(
            dtT, xcT, dblb, A_log + (size_t)l*DI*NST, Pe, He);
        scan_p2T<<<(BB*DI*NC)/4, 256, 0, stream>>>(
            dtT, xcT, zT, dblb, A_log + (size_t)l*DI*NST, Dp + (size_t)l*DI,
            Pe, He, yTb);
        transpose_bf<<<dim3(ROWS/64, DI/64), 256, 0, stream>>>(
            (const u16*)yTb, (u16*)ybf, ROWS, DI);
        // out_proj + residual
        gemm_mfma<DI><<<dim3(DM/64, ROWS/64), 256, 0, stream>>>(
            ybf, w_out + (size_t)l*DM*DI, out, nullptr, xin, DM, 2);
    }
}

// Round 12
// 311.821 us; speedup vs baseline: 3.3122x; 1.0090x over previous
//
#include <hip/hip_runtime.h>
#include <math.h>

#define DI 512
#define DM 256
#define LSEQ 1024
#define BB 4
#define NST 64
#define ROWS (BB*LSEQ)   // 4096
#define NC 16            // chunks per sequence
#define CL 64            // chunk length

typedef __bf16 bf16x8 __attribute__((ext_vector_type(8)));
typedef __bf16 bf16x4 __attribute__((ext_vector_type(4)));
typedef float f32x4 __attribute__((ext_vector_type(4)));
typedef unsigned short u16;
typedef u16 u16x8 __attribute__((ext_vector_type(8)));
typedef int i32x2 __attribute__((ext_vector_type(2)));

__device__ __forceinline__ float siluf(float x) { return x / (1.f + __expf(-x)); }
__device__ __forceinline__ float softplusf(float x) { return (x > 20.f) ? x : log1pf(__expf(x)); }
__device__ __forceinline__ float rlane(float v, int l) {
    return __int_as_float(__builtin_amdgcn_readlane(__float_as_int(v), l));
}
__device__ __forceinline__ float fexp2(float x) {
#if __has_builtin(__builtin_amdgcn_exp2f)
    return __builtin_amdgcn_exp2f(x);
#else
    return __expf(x * 0.69314718056f);
#endif
}
template<int PAT>
__device__ __forceinline__ float fswz(float v) {
    return __int_as_float(__builtin_amdgcn_ds_swizzle(__float_as_int(v), PAT));
}

// pairing-tree reduction: sums s[0..7] (each across all 64 lanes).
// Result: lane L holds total of s[L>>3].
__device__ __forceinline__ float tree8(const float (&s)[8], int lane) {
    const bool b4 = (lane & 16) != 0;
    const bool b3 = (lane & 8) != 0;
    float r[4];
#if __has_builtin(__builtin_amdgcn_permlane32_swap)
    #pragma unroll
    for (int i = 0; i < 4; ++i) {
        i32x2 pr = __builtin_amdgcn_permlane32_swap(
            __float_as_int(s[i]), __float_as_int(s[i+4]), false, false);
        r[i] = __int_as_float(pr[0]) + __int_as_float(pr[1]);
    }
#else
    const bool b5 = (lane & 32) != 0;
    #pragma unroll
    for (int i = 0; i < 4; ++i) {
        float u = b5 ? s[i+4] : s[i];
        float w = b5 ? s[i]   : s[i+4];
        r[i] = u + __shfl_xor(w, 32, 64);
    }
#endif
    float q[2];
    #pragma unroll
    for (int i = 0; i < 2; ++i) {
        float u = b4 ? r[i+2] : r[i];
        float w = b4 ? r[i]   : r[i+2];
        q[i] = u + fswz<0x401F>(w);   // xor 16 (within 32-group)
    }
    float u = b3 ? q[1] : q[0];
    float w = b3 ? q[0] : q[1];
    float p = u + fswz<0x201F>(w);    // xor 8
    p += fswz<0x101F>(p);             // xor 4
    p += fswz<0x081F>(p);             // xor 2
    p += fswz<0x041F>(p);             // xor 1
    return p;
}

// ---------------- float -> bf16 convert (weights) -------------------
__global__ __launch_bounds__(256) void f2bf(
    const float* __restrict__ in, __bf16* __restrict__ out, int n)
{
    int i = (blockIdx.x * 256 + threadIdx.x) * 4;
    if (i >= n) return;
    float4 v = *(const float4*)(in + i);
    bf16x4 o;
    o[0] = (__bf16)v.x; o[1] = (__bf16)v.y; o[2] = (__bf16)v.z; o[3] = (__bf16)v.w;
    *(bf16x4*)(out + i) = o;
}

// ---------------- LayerNorm: one wave per row of 256, bf16 out ------
__global__ __launch_bounds__(256) void ln_kernel(
    const float* __restrict__ x, const float* __restrict__ g,
    const float* __restrict__ b, __bf16* __restrict__ xn)
{
    int lane = threadIdx.x & 63;
    int row = blockIdx.x * 4 + (threadIdx.x >> 6);
    const float4* xr = (const float4*)(x + (size_t)row * DM);
    float4 v = xr[lane];
    float s = v.x + v.y + v.z + v.w;
    #pragma unroll
    for (int o = 32; o; o >>= 1) s += __shfl_xor(s, o, 64);
    float mu = s * (1.f / DM);
    float dx = v.x - mu, dy = v.y - mu, dz = v.z - mu, dw = v.w - mu;
    float q = dx*dx + dy*dy + dz*dz + dw*dw;
    #pragma unroll
    for (int o = 32; o; o >>= 1) q += __shfl_xor(q, o, 64);
    float inv = rsqrtf(q * (1.f / DM) + 1e-5f);
    float4 gv = ((const float4*)g)[lane];
    float4 bv = ((const float4*)b)[lane];
    bf16x4 o4;
    o4[0] = (__bf16)(dx * inv * gv.x + bv.x);
    o4[1] = (__bf16)(dy * inv * gv.y + bv.y);
    o4[2] = (__bf16)(dz * inv * gv.z + bv.z);
    o4[3] = (__bf16)(dw * inv * gv.w + bv.w);
    *(bf16x4*)(xn + (size_t)row * DM + lane * 4) = o4;
}

// ------------- bf16 MFMA GEMM: C[M,N] = A[M,K] @ W[N,K]^T -----------
template<int KK>
__global__ __launch_bounds__(256) void gemm_mfma(
    const __bf16* __restrict__ A, const __bf16* __restrict__ W,
    float* __restrict__ C, __bf16* __restrict__ C2b,
    const float* __restrict__ res, int N, int mode)
{
    int wid = threadIdx.x >> 6, lane = threadIdx.x & 63;
    int wr = wid >> 1, wc = wid & 1;
    int bm = blockIdx.y * 64, bn = blockIdx.x * 64;
    int l15 = lane & 15, lk = (lane >> 4) * 8;
    const __bf16* Ap = A + (size_t)(bm + wr*32 + l15) * KK + lk;
    int wrow0 = bn + wc*32 + l15;
    int wrow1 = wrow0 + 16;
    if (wrow0 > N-1) wrow0 = N-1;
    if (wrow1 > N-1) wrow1 = N-1;
    const __bf16* Wp0 = W + (size_t)wrow0 * KK + lk;
    const __bf16* Wp1 = W + (size_t)wrow1 * KK + lk;
    f32x4 acc[2][2] = {};
    #pragma unroll 4
    for (int k0 = 0; k0 < KK; k0 += 32) {
        bf16x8 b0 = *(const bf16x8*)(Wp0 + k0);
        bf16x8 b1 = *(const bf16x8*)(Wp1 + k0);
        #pragma unroll
        for (int m = 0; m < 2; ++m) {
            bf16x8 a = *(const bf16x8*)(Ap + (size_t)m*16*KK + k0);
            acc[m][0] = __builtin_amdgcn_mfma_f32_16x16x32_bf16(a, b0, acc[m][0], 0, 0, 0);
            acc[m][1] = __builtin_amdgcn_mfma_f32_16x16x32_bf16(a, b1, acc[m][1], 0, 0, 0);
        }
    }
    int r4 = (lane >> 4) * 4;
    #pragma unroll
    for (int m = 0; m < 2; ++m) {
        int row = bm + wr*32 + m*16 + r4;
        #pragma unroll
        for (int n = 0; n < 2; ++n) {
            int col = bn + wc*32 + n*16 + l15;
            #pragma unroll
            for (int r = 0; r < 4; ++r) {
                float v = acc[m][n][r];
                int rr = row + r;
                if (mode == 0) {
                    if (col < N) C[(size_t)rr * N + col] = v;
                } else if (mode == 1) {
                    if (col < 512) C[(size_t)rr * 512 + col] = v;
                    else           C2b[(size_t)rr * 512 + col - 512] = (__bf16)v;
                } else {
                    C[(size_t)rr * N + col] = v + res[(size_t)rr * N + col];
                }
            }
        }
    }
}

// -------- fp32 tiled GEMM (dt projection, K=16) -> TRANSPOSED out ----
__global__ __launch_bounds__(256) void gemm_dt(
    const float* __restrict__ A, int lda,
    const float* __restrict__ W,
    float* __restrict__ CT, const float* __restrict__ aux)
{
    __shared__ float As[16][68];
    __shared__ float Ws[16][68];
    const int bm = blockIdx.y * 64;
    const int bn = blockIdx.x * 64;
    const int tid = threadIdx.x;
    const int tx = tid & 15;
    const int ty = tid >> 4;
    const int lr = tid >> 2;
    const int lc = (tid & 3) << 2;
    float acc[4][4] = {};
    {
        float4 av = *(const float4*)(A + (size_t)(bm + lr) * lda + lc);
        float4 wv = *(const float4*)(W + (size_t)(bn + lr) * 16 + lc);
        As[lc+0][lr] = av.x; As[lc+1][lr] = av.y; As[lc+2][lr] = av.z; As[lc+3][lr] = av.w;
        Ws[lc+0][lr] = wv.x; Ws[lc+1][lr] = wv.y; Ws[lc+2][lr] = wv.z; Ws[lc+3][lr] = wv.w;
        __syncthreads();
        #pragma unroll
        for (int k = 0; k < 16; ++k) {
            float a[4], w[4];
            #pragma unroll
            for (int i = 0; i < 4; ++i) a[i] = As[k][ty*4 + i];
            #pragma unroll
            for (int j = 0; j < 4; ++j) w[j] = Ws[k][tx*4 + j];
            #pragma unroll
            for (int i = 0; i < 4; ++i)
                #pragma unroll
                for (int j = 0; j < 4; ++j)
                    acc[i][j] = fmaf(a[i], w[j], acc[i][j]);
        }
    }
    #pragma unroll
    for (int j = 0; j < 4; ++j) {
        int n = bn + tx*4 + j;
        float bia = aux[n];
        float4 v;
        v.x = softplusf(acc[0][j] + bia);
        v.y = softplusf(acc[1][j] + bia);
        v.z = softplusf(acc[2][j] + bia);
        v.w = softplusf(acc[3][j] + bia);
        *(float4*)(CT + (size_t)n * ROWS + bm + ty*4) = v;
    }
}

// --- fused: conv(k=4)+SiLU with dual-layout out, plus z transpose ----
__global__ __launch_bounds__(256) void conv_tr_kernel(
    const float* __restrict__ xm, const float* __restrict__ cw,
    const float* __restrict__ cb, const u16* __restrict__ zin,
    __bf16* __restrict__ xcb, u16* __restrict__ xcT, u16* __restrict__ zT)
{
    __shared__ float xs[67][66];
    __shared__ u16 Tc[64][72];
    __shared__ u16 Tz[64][72];
    const int tid = threadIdx.x;
    const int row0 = blockIdx.y * 64;
    const int d0 = blockIdx.x * 64;
    #pragma unroll
    for (int it = 0; it < 5; ++it) {
        int f4 = it * 256 + tid;
        if (f4 < 67 * 16) {
            int rr = f4 >> 4;
            int cc = (f4 & 15) * 4;
            int g = row0 - 3 + rr;
            float4 v = make_float4(0.f, 0.f, 0.f, 0.f);
            if (g >= 0 && (g >> 10) == (row0 >> 10))
                v = *(const float4*)(xm + (size_t)g * DI + d0 + cc);
            *(float4*)&xs[rr][cc] = v;
        }
    }
    const int r = tid >> 2;
    const int c0 = (tid & 3) * 16;
    {
        const u16* zp = zin + (size_t)(row0 + r) * DI + d0 + c0;
        *(u16x8*)&Tz[r][c0]     = *(const u16x8*)(zp);
        *(u16x8*)&Tz[r][c0 + 8] = *(const u16x8*)(zp + 8);
    }
    __syncthreads();
    {
        bf16x8 v0, v1;
        #pragma unroll
        for (int j = 0; j < 16; ++j) {
            int d = d0 + c0 + j;
            float acc = cb[d]
                + xs[r+0][c0+j] * cw[d*4+0]
                + xs[r+1][c0+j] * cw[d*4+1]
                + xs[r+2][c0+j] * cw[d*4+2]
                + xs[r+3][c0+j] * cw[d*4+3];
            __bf16 o = (__bf16)siluf(acc);
            if (j < 8) v0[j] = o; else v1[j-8] = o;
            Tc[r][c0+j] = *(const u16*)&o;
        }
        __bf16* op = xcb + (size_t)(row0 + r) * DI + d0 + c0;
        *(bf16x8*)(op)     = v0;
        *(bf16x8*)(op + 8) = v1;
    }
    __syncthreads();
    {
        u16x8 a0, a1, b0, b1;
        #pragma unroll
        for (int i = 0; i < 8; ++i) {
            a0[i] = Tc[c0+i][r];   a1[i] = Tc[c0+8+i][r];
            b0[i] = Tz[c0+i][r];   b1[i] = Tz[c0+8+i][r];
        }
        u16* oc = xcT + (size_t)(d0 + r) * ROWS + row0 + c0;
        u16* oz = zT  + (size_t)(d0 + r) * ROWS + row0 + c0;
        *(u16x8*)(oc)     = a0;
        *(u16x8*)(oc + 8) = a1;
        *(u16x8*)(oz)     = b0;
        *(u16x8*)(oz + 8) = b1;
    }
}

// ----- bf16 transpose tile 64x64: ld=ldi -> out ld=ldo (y only) -----
__global__ __launch_bounds__(256) void transpose_bf(
    const u16* __restrict__ in, u16* __restrict__ out, int ldi, int ldo)
{
    __shared__ u16 tile[64][72];
    int r = threadIdx.x >> 2;
    int c0 = (threadIdx.x & 3) * 16;
    const u16* ip = in + (size_t)(blockIdx.y*64 + r) * ldi + blockIdx.x*64 + c0;
    *(u16x8*)&tile[r][c0]     = *(const u16x8*)(ip);
    *(u16x8*)&tile[r][c0 + 8] = *(const u16x8*)(ip + 8);
    __syncthreads();
    u16* op = out + (size_t)(blockIdx.x*64 + r) * ldo + blockIdx.y*64 + c0;
    u16x8 v0, v1;
    #pragma unroll
    for (int i = 0; i < 8; ++i) { v0[i] = tile[c0+i][r]; v1[i] = tile[c0+8+i][r]; }
    *(u16x8*)(op)     = v0;
    *(u16x8*)(op + 8) = v1;
}

// -------- scan pass 1: per-chunk (P_end, H_end), transposed in -------
__global__ __launch_bounds__(256) void scan_p1T(
    const float* __restrict__ dtT, const __bf16* __restrict__ xcT,
    const float* __restrict__ dbl, const float* __restrict__ A_log,
    float* __restrict__ Pe, float* __restrict__ He)
{
    int wid = (blockIdx.x * 256 + threadIdx.x) >> 6;
    int lane = threadIdx.x & 63;
    int c = wid & (NC - 1);
    int d = (wid >> 4) & (DI - 1);
    int b = wid >> 13;
    float An2 = -__expf(A_log[d * NST + lane]) * 1.44269504f;
    size_t row0 = (size_t)b * LSEQ + (size_t)c * CL;
    size_t tix = (size_t)d * ROWS + row0;
    float dtv = dtT[tix + lane];
    float uvf = (float)xcT[tix + lane];
    float duv = dtv * uvf;
    float Sdt = dtv;
    #pragma unroll
    for (int o = 32; o; o >>= 1) Sdt += __shfl_xor(Sdt, o, 64);
    const float* bp = dbl + row0 * 144 + 16 + lane;
    float H = 0.f;
    #pragma unroll
    for (int j = 0; j < 8; ++j) {
        #pragma unroll
        for (int q = 0; q < 8; ++q) {
            const int t = 8*j + q;
            float dA = fexp2(rlane(dtv, t) * An2);
            H = fmaf(dA, H, rlane(duv, t) * bp[q * 144]);
        }
        bp += 8 * 144;
    }
    size_t o = (size_t)wid * 64 + lane;
    Pe[o] = fexp2(An2 * Sdt);
    He[o] = H;
}

// -------- carry: combine chunk (P,H) chains; slot j := h after 0..j --
__global__ __launch_bounds__(256) void scan_carry(
    float* __restrict__ Pe, const float* __restrict__ He)
{
    int wid = (blockIdx.x * 256 + threadIdx.x) >> 6;   // (b,d)
    int lane = threadIdx.x & 63;
    size_t base = (size_t)wid * NC * 64 + lane;
    float p[15], q[15];
    #pragma unroll
    for (int j = 0; j < 15; ++j) {
        p[j] = Pe[base + (size_t)j * 64];
        q[j] = He[base + (size_t)j * 64];
    }
    float h = 0.f;
    #pragma unroll
    for (int j = 0; j < 15; ++j) {
        h = fmaf(p[j], h, q[j]);
        Pe[base + (size_t)j * 64] = h;
    }
}

// -------- scan pass 2: seeded single pass, emit bf16 yT --------------
__global__ __launch_bounds__(256) void scan_p2T(
    const float* __restrict__ dtT, const __bf16* __restrict__ xcT,
    const __bf16* __restrict__ zT, const float* __restrict__ dbl,
    const float* __restrict__ A_log, const float* __restrict__ Dp,
    const float* __restrict__ Pe, __bf16* __restrict__ yT)
{
    __shared__ float Ys[4][64];
    int wid = (blockIdx.x * 256 + threadIdx.x) >> 6;
    int w = threadIdx.x >> 6;
    int lane = threadIdx.x & 63;
    int c = wid & (NC - 1);
    int d = (wid >> 4) & (DI - 1);
    int b = wid >> 13;
    float An2 = -__expf(A_log[d * NST + lane]) * 1.44269504f;
    size_t row0 = (size_t)b * LSEQ + (size_t)c * CL;
    size_t tix = (size_t)d * ROWS + row0;
    float dtv = dtT[tix + lane];
    float uvf = (float)xcT[tix + lane];
    float zvf = (float)zT[tix + lane];
    float duv = dtv * uvf;
    float gD  = uvf * Dp[d];
    float wz  = siluf(zvf);
    float h = (c == 0) ? 0.f : Pe[(size_t)(wid - 1) * 64 + lane];
    const float* bp = dbl + row0 * 144 + 16 + lane;
    const float* cp = dbl + row0 * 144 + 80 + lane;
    float yred[8];
    #pragma unroll
    for (int j = 0; j < 8; ++j) {
        float s[8];
        #pragma unroll
        for (int q = 0; q < 8; ++q) {
            const int t = 8*j + q;
            float dA = fexp2(rlane(dtv, t) * An2);
            h = fmaf(dA, h, rlane(duv, t) * bp[q * 144]);
            s[q] = h * cp[q * 144];
        }
        yred[j] = tree8(s, lane);
        bp += 8 * 144;
        cp += 8 * 144;
    }
    if ((lane & 7) == 0) {
        #pragma unroll
        for (int j = 0; j < 8; ++j) Ys[w][8*j + (lane >> 3)] = yred[j];
    }
    float y = (Ys[w][lane] + gD) * wz;
    yT[tix + lane] = (__bf16)y;
}

extern "C" void kernel_launch(void* const* d_in, const int* in_sizes, int n_in,
                              void* d_out, int out_size, void* d_ws, size_t ws_size,
                              hipStream_t stream)
{
    const float* x      = (const float*)d_in[0];
    const float* ln_g   = (const float*)d_in[1];
    const float* ln_b   = (const float*)d_in[2];
    const float* in_w   = (const float*)d_in[3];
    const float* conv_w = (const float*)d_in[4];
    const float* conv_b = (const float*)d_in[5];
    const float* xp_w   = (const float*)d_in[6];
    const float* dt_w   = (const float*)d_in[7];
    const float* dt_b   = (const float*)d_in[8];
    const float* A_log  = (const float*)d_in[9];
    const float* Dp     = (const float*)d_in[10];
    const float* out_w  = (const float*)d_in[11];
    float* out = (float*)d_out;

    char* ws = (char*)d_ws;
    const size_t MB = 1u << 20;
    float*  xm   = (float*)(ws + 0*MB);    // conv input; dead after conv_tr
    float*  Pe   = (float*)(ws + 0*MB);    //   then p1 P / carry h0
    float*  dtT  = (float*)(ws + 8*MB);    // [512][4096] fp32
    __bf16* xcbf = (__bf16*)(ws + 16*MB);  // conv out [4096][512]; dead after x_proj
    __bf16* yTb  = (__bf16*)(ws + 16*MB);  //   then scan out [512][4096]
    __bf16* xcT  = (__bf16*)(ws + 20*MB);  // [512][4096]
    __bf16* zbf  = (__bf16*)(ws + 24*MB);  // in_proj z; dead after conv_tr
    __bf16* ybf  = (__bf16*)(ws + 24*MB);  //   then y re-transposed [4096][512]
    __bf16* zT   = (__bf16*)(ws + 28*MB);  // [512][4096]
    float*  He   = (float*)(ws + 32*MB);   // p1 H
    float*  dblb = (float*)(ws + 40*MB);   // 2.25 MB
    __bf16* xnb  = (__bf16*)(ws + 43*MB);  // LN out (2 MB)
    __bf16* w_in  = (__bf16*)(ws + 45*MB);
    __bf16* w_xp  = (__bf16*)(ws + 46*MB);
    __bf16* w_out = (__bf16*)(ws + 46*MB + 512*1024);

    f2bf<<<512, 256, 0, stream>>>(in_w,  w_in,  2*1024*DM);
    f2bf<<<144, 256, 0, stream>>>(xp_w,  w_xp,  2*144*DI);
    f2bf<<<256, 256, 0, stream>>>(out_w, w_out, 2*DM*DI);

    for (int l = 0; l < 2; ++l) {
        const float* xin = (l == 0) ? x : out;
        ln_kernel<<<ROWS/4, 256, 0, stream>>>(xin, ln_g + l*DM, ln_b + l*DM, xnb);
        // in_proj -> xm fp32 | z bf16
        gemm_mfma<DM><<<dim3(1024/64, ROWS/64), 256, 0, stream>>>(
            xnb, w_in + (size_t)l*1024*DM, xm, zbf, nullptr, 1024, 1);
        // fused conv+silu (dual layout) + z transpose
        conv_tr_kernel<<<dim3(DI/64, ROWS/64), 256, 0, stream>>>(
            xm, conv_w + (size_t)l*DI*4, conv_b + (size_t)l*DI,
            (const u16*)zbf, xcbf, (u16*)xcT, (u16*)zT);
        // x_proj -> dbl fp32
        gemm_mfma<DI><<<dim3(3, ROWS/64), 256, 0, stream>>>(
            xcbf, w_xp + (size_t)l*144*DI, dblb, nullptr, nullptr, 144, 0);
        // dt projection, transposed fp32 out + softplus
        gemm_dt<<<dim3(DI/64, ROWS/64), 256, 0, stream>>>(
            dblb, 144, dt_w + (size_t)l*DI*16, dtT, dt_b + (size_t)l*DI);
        // chunked scan: p1 -> carry -> p2 (seeded)
        scan_p1T<<<(BB*DI*NC)/4, 256, 0, stream>>>(
            dtT, xcT, dblb, A_log + (size_t)l*DI*NST, Pe, He);
        scan_carry<<<(BB*DI)/4, 256, 0, stream>>>(Pe, He);
        scan_p2T<<<(BB*DI*NC)/4, 256, 0, stream>>>(
            dtT, xcT, zT, dblb, A_log + (size_t)l*DI*NST, Dp + (size_t)l*DI,
            Pe, yTb);
        transpose_bf<<<dim3(ROWS/64, DI/64), 256, 0, stream>>>(
            (const u16*)yTb, (u16*)ybf, ROWS, DI);
        // out_proj + residual
        gemm_mfma<DI><<<dim3(DM/64, ROWS/64), 256, 0, stream>>>(
            ybf, w_out + (size_t)l*DM*DI, out, nullptr, xin, DM, 2);
    }
}

// Round 13
// 287.962 us; speedup vs baseline: 3.5866x; 1.0829x over previous
//
#include <hip/hip_runtime.h>
#include <math.h>

#define DI 512
#define DM 256
#define LSEQ 1024
#define BB 4
#define NST 64
#define ROWS (BB*LSEQ)   // 4096
#define NC 16            // chunks per sequence
#define CL 64            // chunk length

typedef __bf16 bf16x8 __attribute__((ext_vector_type(8)));
typedef __bf16 bf16x4 __attribute__((ext_vector_type(4)));
typedef float f32x4 __attribute__((ext_vector_type(4)));
typedef unsigned short u16;
typedef u16 u16x8 __attribute__((ext_vector_type(8)));
typedef int i32x2 __attribute__((ext_vector_type(2)));

__device__ __forceinline__ float siluf(float x) { return x / (1.f + __expf(-x)); }
__device__ __forceinline__ float softplusf(float x) { return (x > 20.f) ? x : log1pf(__expf(x)); }
__device__ __forceinline__ float rlane(float v, int l) {
    return __int_as_float(__builtin_amdgcn_readlane(__float_as_int(v), l));
}
__device__ __forceinline__ float fexp2(float x) {
#if __has_builtin(__builtin_amdgcn_exp2f)
    return __builtin_amdgcn_exp2f(x);
#else
    return __expf(x * 0.69314718056f);
#endif
}
template<int PAT>
__device__ __forceinline__ float fswz(float v) {
    return __int_as_float(__builtin_amdgcn_ds_swizzle(__float_as_int(v), PAT));
}

// pairing-tree reduction: sums s[0..7] (each across all 64 lanes).
// Result: lane L holds total of s[L>>3].
__device__ __forceinline__ float tree8(const float (&s)[8], int lane) {
    const bool b4 = (lane & 16) != 0;
    const bool b3 = (lane & 8) != 0;
    float r[4];
#if __has_builtin(__builtin_amdgcn_permlane32_swap)
    #pragma unroll
    for (int i = 0; i < 4; ++i) {
        i32x2 pr = __builtin_amdgcn_permlane32_swap(
            __float_as_int(s[i]), __float_as_int(s[i+4]), false, false);
        r[i] = __int_as_float(pr[0]) + __int_as_float(pr[1]);
    }
#else
    const bool b5 = (lane & 32) != 0;
    #pragma unroll
    for (int i = 0; i < 4; ++i) {
        float u = b5 ? s[i+4] : s[i];
        float w = b5 ? s[i]   : s[i+4];
        r[i] = u + __shfl_xor(w, 32, 64);
    }
#endif
    float q[2];
    #pragma unroll
    for (int i = 0; i < 2; ++i) {
        float u = b4 ? r[i+2] : r[i];
        float w = b4 ? r[i]   : r[i+2];
        q[i] = u + fswz<0x401F>(w);   // xor 16 (within 32-group)
    }
    float u = b3 ? q[1] : q[0];
    float w = b3 ? q[0] : q[1];
    float p = u + fswz<0x201F>(w);    // xor 8
    p += fswz<0x101F>(p);             // xor 4
    p += fswz<0x081F>(p);             // xor 2
    p += fswz<0x041F>(p);             // xor 1
    return p;
}

// ------------- merged float -> bf16 convert (3 weight arrays) --------
__global__ __launch_bounds__(256) void f2bf3(
    const float* __restrict__ a, __bf16* __restrict__ da, int na,
    const float* __restrict__ b, __bf16* __restrict__ db, int nb,
    const float* __restrict__ c, __bf16* __restrict__ dc, int nc)
{
    int i = (blockIdx.x * 256 + threadIdx.x) * 4;
    const float* src; __bf16* dst;
    if (i < na) { src = a + i; dst = da + i; }
    else {
        i -= na;
        if (i < nb) { src = b + i; dst = db + i; }
        else {
            i -= nb;
            if (i >= nc) return;
            src = c + i; dst = dc + i;
        }
    }
    float4 v = *(const float4*)src;
    bf16x4 o;
    o[0] = (__bf16)v.x; o[1] = (__bf16)v.y; o[2] = (__bf16)v.z; o[3] = (__bf16)v.w;
    *(bf16x4*)dst = o;
}

// ---------------- LayerNorm: one wave per row of 256, bf16 out ------
__global__ __launch_bounds__(256) void ln_kernel(
    const float* __restrict__ x, const float* __restrict__ g,
    const float* __restrict__ b, __bf16* __restrict__ xn)
{
    int lane = threadIdx.x & 63;
    int row = blockIdx.x * 4 + (threadIdx.x >> 6);
    const float4* xr = (const float4*)(x + (size_t)row * DM);
    float4 v = xr[lane];
    float s = v.x + v.y + v.z + v.w;
    #pragma unroll
    for (int o = 32; o; o >>= 1) s += __shfl_xor(s, o, 64);
    float mu = s * (1.f / DM);
    float dx = v.x - mu, dy = v.y - mu, dz = v.z - mu, dw = v.w - mu;
    float q = dx*dx + dy*dy + dz*dz + dw*dw;
    #pragma unroll
    for (int o = 32; o; o >>= 1) q += __shfl_xor(q, o, 64);
    float inv = rsqrtf(q * (1.f / DM) + 1e-5f);
    float4 gv = ((const float4*)g)[lane];
    float4 bv = ((const float4*)b)[lane];
    bf16x4 o4;
    o4[0] = (__bf16)(dx * inv * gv.x + bv.x);
    o4[1] = (__bf16)(dy * inv * gv.y + bv.y);
    o4[2] = (__bf16)(dz * inv * gv.z + bv.z);
    o4[3] = (__bf16)(dw * inv * gv.w + bv.w);
    *(bf16x4*)(xn + (size_t)row * DM + lane * 4) = o4;
}

// ------------- bf16 MFMA GEMM: C[M,N] = A[M,K] @ W[N,K]^T -----------
template<int KK>
__global__ __launch_bounds__(256) void gemm_mfma(
    const __bf16* __restrict__ A, const __bf16* __restrict__ W,
    float* __restrict__ C, __bf16* __restrict__ C2b,
    const float* __restrict__ res, int N, int mode)
{
    int wid = threadIdx.x >> 6, lane = threadIdx.x & 63;
    int wr = wid >> 1, wc = wid & 1;
    int bm = blockIdx.y * 64, bn = blockIdx.x * 64;
    int l15 = lane & 15, lk = (lane >> 4) * 8;
    const __bf16* Ap = A + (size_t)(bm + wr*32 + l15) * KK + lk;
    int wrow0 = bn + wc*32 + l15;
    int wrow1 = wrow0 + 16;
    if (wrow0 > N-1) wrow0 = N-1;
    if (wrow1 > N-1) wrow1 = N-1;
    const __bf16* Wp0 = W + (size_t)wrow0 * KK + lk;
    const __bf16* Wp1 = W + (size_t)wrow1 * KK + lk;
    f32x4 acc[2][2] = {};
    #pragma unroll 4
    for (int k0 = 0; k0 < KK; k0 += 32) {
        bf16x8 b0 = *(const bf16x8*)(Wp0 + k0);
        bf16x8 b1 = *(const bf16x8*)(Wp1 + k0);
        #pragma unroll
        for (int m = 0; m < 2; ++m) {
            bf16x8 a = *(const bf16x8*)(Ap + (size_t)m*16*KK + k0);
            acc[m][0] = __builtin_amdgcn_mfma_f32_16x16x32_bf16(a, b0, acc[m][0], 0, 0, 0);
            acc[m][1] = __builtin_amdgcn_mfma_f32_16x16x32_bf16(a, b1, acc[m][1], 0, 0, 0);
        }
    }
    int r4 = (lane >> 4) * 4;
    #pragma unroll
    for (int m = 0; m < 2; ++m) {
        int row = bm + wr*32 + m*16 + r4;
        #pragma unroll
        for (int n = 0; n < 2; ++n) {
            int col = bn + wc*32 + n*16 + l15;
            #pragma unroll
            for (int r = 0; r < 4; ++r) {
                float v = acc[m][n][r];
                int rr = row + r;
                if (mode == 0) {
                    if (col < N) C[(size_t)rr * N + col] = v;
                } else if (mode == 1) {
                    if (col < 512) C[(size_t)rr * 512 + col] = v;
                    else           C2b[(size_t)rr * 512 + col - 512] = (__bf16)v;
                } else {
                    C[(size_t)rr * N + col] = v + res[(size_t)rr * N + col];
                }
            }
        }
    }
}

// -------- fp32 tiled GEMM (dt projection, K=16) -> TRANSPOSED out ----
__global__ __launch_bounds__(256) void gemm_dt(
    const float* __restrict__ A, int lda,
    const float* __restrict__ W,
    float* __restrict__ CT, const float* __restrict__ aux)
{
    __shared__ float As[16][68];
    __shared__ float Ws[16][68];
    const int bm = blockIdx.y * 64;
    const int bn = blockIdx.x * 64;
    const int tid = threadIdx.x;
    const int tx = tid & 15;
    const int ty = tid >> 4;
    const int lr = tid >> 2;
    const int lc = (tid & 3) << 2;
    float acc[4][4] = {};
    {
        float4 av = *(const float4*)(A + (size_t)(bm + lr) * lda + lc);
        float4 wv = *(const float4*)(W + (size_t)(bn + lr) * 16 + lc);
        As[lc+0][lr] = av.x; As[lc+1][lr] = av.y; As[lc+2][lr] = av.z; As[lc+3][lr] = av.w;
        Ws[lc+0][lr] = wv.x; Ws[lc+1][lr] = wv.y; Ws[lc+2][lr] = wv.z; Ws[lc+3][lr] = wv.w;
        __syncthreads();
        #pragma unroll
        for (int k = 0; k < 16; ++k) {
            float a[4], w[4];
            #pragma unroll
            for (int i = 0; i < 4; ++i) a[i] = As[k][ty*4 + i];
            #pragma unroll
            for (int j = 0; j < 4; ++j) w[j] = Ws[k][tx*4 + j];
            #pragma unroll
            for (int i = 0; i < 4; ++i)
                #pragma unroll
                for (int j = 0; j < 4; ++j)
                    acc[i][j] = fmaf(a[i], w[j], acc[i][j]);
        }
    }
    #pragma unroll
    for (int j = 0; j < 4; ++j) {
        int n = bn + tx*4 + j;
        float bia = aux[n];
        float4 v;
        v.x = softplusf(acc[0][j] + bia);
        v.y = softplusf(acc[1][j] + bia);
        v.z = softplusf(acc[2][j] + bia);
        v.w = softplusf(acc[3][j] + bia);
        *(float4*)(CT + (size_t)n * ROWS + bm + ty*4) = v;
    }
}

// --- fused: conv(k=4)+SiLU with dual-layout out, plus z transpose ----
__global__ __launch_bounds__(256) void conv_tr_kernel(
    const float* __restrict__ xm, const float* __restrict__ cw,
    const float* __restrict__ cb, const u16* __restrict__ zin,
    __bf16* __restrict__ xcb, u16* __restrict__ xcT, u16* __restrict__ zT)
{
    __shared__ float xs[67][66];
    __shared__ u16 Tc[64][72];
    __shared__ u16 Tz[64][72];
    const int tid = threadIdx.x;
    const int row0 = blockIdx.y * 64;
    const int d0 = blockIdx.x * 64;
    #pragma unroll
    for (int it = 0; it < 5; ++it) {
        int f4 = it * 256 + tid;
        if (f4 < 67 * 16) {
            int rr = f4 >> 4;
            int cc = (f4 & 15) * 4;
            int g = row0 - 3 + rr;
            float4 v = make_float4(0.f, 0.f, 0.f, 0.f);
            if (g >= 0 && (g >> 10) == (row0 >> 10))
                v = *(const float4*)(xm + (size_t)g * DI + d0 + cc);
            *(float4*)&xs[rr][cc] = v;
        }
    }
    const int r = tid >> 2;
    const int c0 = (tid & 3) * 16;
    {
        const u16* zp = zin + (size_t)(row0 + r) * DI + d0 + c0;
        *(u16x8*)&Tz[r][c0]     = *(const u16x8*)(zp);
        *(u16x8*)&Tz[r][c0 + 8] = *(const u16x8*)(zp + 8);
    }
    __syncthreads();
    {
        bf16x8 v0, v1;
        #pragma unroll
        for (int j = 0; j < 16; ++j) {
            int d = d0 + c0 + j;
            float acc = cb[d]
                + xs[r+0][c0+j] * cw[d*4+0]
                + xs[r+1][c0+j] * cw[d*4+1]
                + xs[r+2][c0+j] * cw[d*4+2]
                + xs[r+3][c0+j] * cw[d*4+3];
            __bf16 o = (__bf16)siluf(acc);
            if (j < 8) v0[j] = o; else v1[j-8] = o;
            Tc[r][c0+j] = *(const u16*)&o;
        }
        __bf16* op = xcb + (size_t)(row0 + r) * DI + d0 + c0;
        *(bf16x8*)(op)     = v0;
        *(bf16x8*)(op + 8) = v1;
    }
    __syncthreads();
    {
        u16x8 a0, a1, b0, b1;
        #pragma unroll
        for (int i = 0; i < 8; ++i) {
            a0[i] = Tc[c0+i][r];   a1[i] = Tc[c0+8+i][r];
            b0[i] = Tz[c0+i][r];   b1[i] = Tz[c0+8+i][r];
        }
        u16* oc = xcT + (size_t)(d0 + r) * ROWS + row0 + c0;
        u16* oz = zT  + (size_t)(d0 + r) * ROWS + row0 + c0;
        *(u16x8*)(oc)     = a0;
        *(u16x8*)(oc + 8) = a1;
        *(u16x8*)(oz)     = b0;
        *(u16x8*)(oz + 8) = b1;
    }
}

// ----- bf16 transpose tile 64x64: ld=ldi -> out ld=ldo (y only) -----
__global__ __launch_bounds__(256) void transpose_bf(
    const u16* __restrict__ in, u16* __restrict__ out, int ldi, int ldo)
{
    __shared__ u16 tile[64][72];
    int r = threadIdx.x >> 2;
    int c0 = (threadIdx.x & 3) * 16;
    const u16* ip = in + (size_t)(blockIdx.y*64 + r) * ldi + blockIdx.x*64 + c0;
    *(u16x8*)&tile[r][c0]     = *(const u16x8*)(ip);
    *(u16x8*)&tile[r][c0 + 8] = *(const u16x8*)(ip + 8);
    __syncthreads();
    u16* op = out + (size_t)(blockIdx.x*64 + r) * ldo + blockIdx.y*64 + c0;
    u16x8 v0, v1;
    #pragma unroll
    for (int i = 0; i < 8; ++i) { v0[i] = tile[c0+i][r]; v1[i] = tile[c0+8+i][r]; }
    *(u16x8*)(op)     = v0;
    *(u16x8*)(op + 8) = v1;
}

// -------- fused chunked scan: block = (b,d), 4 waves ----------------
// phase1: wave w computes local (P,H) for chunks 3w..3w+2 (only 0..11
// are needed as seed sources). One barrier. phase2: wave w runs seeded
// chunks 4w..4w+3; live h carries exactly across its 4 chunks.
__global__ __launch_bounds__(256) void scan_fused2(
    const float* __restrict__ dtT, const __bf16* __restrict__ xcT,
    const __bf16* __restrict__ zT, const float* __restrict__ dbl,
    const float* __restrict__ A_log, const float* __restrict__ Dp,
    __bf16* __restrict__ yT)
{
    __shared__ float Pa[12][NST];
    __shared__ float Ha[12][NST];
    __shared__ float Ys[4][64];
    const int w = threadIdx.x >> 6;
    const int lane = threadIdx.x & 63;
    const int d = blockIdx.x & (DI - 1);
    const int b = blockIdx.x >> 9;
    const float An2 = -__expf(A_log[d * NST + lane]) * 1.44269504f;
    const float dpd = Dp[d];
    const size_t rowb = (size_t)b * LSEQ;
    const size_t tixb = (size_t)d * ROWS + rowb;

    // ---- phase 1 ----
    #pragma unroll 1
    for (int cc = 0; cc < 3; ++cc) {
        const int c = w * 3 + cc;
        const size_t tix = tixb + (size_t)c * CL;
        float dtv = dtT[tix + lane];
        float uvf = (float)xcT[tix + lane];
        float duv = dtv * uvf;
        float Sdt = dtv;
        #pragma unroll
        for (int o = 32; o; o >>= 1) Sdt += __shfl_xor(Sdt, o, 64);
        const float* bp = dbl + (rowb + (size_t)c * CL) * 144 + 16 + lane;
        float H = 0.f;
        #pragma unroll
        for (int j = 0; j < 8; ++j) {
            #pragma unroll
            for (int q = 0; q < 8; ++q) {
                const int t = 8*j + q;
                float dA = fexp2(rlane(dtv, t) * An2);
                H = fmaf(dA, H, rlane(duv, t) * bp[q * 144]);
            }
            bp += 8 * 144;
        }
        Pa[c][lane] = fexp2(An2 * Sdt);
        Ha[c][lane] = H;
    }
    __syncthreads();

    // ---- seed for chunk 4w: chain chunks 0..4w-1 ----
    float h = 0.f;
    #pragma unroll 1
    for (int j = 0; j < w * 4; ++j)
        h = fmaf(Pa[j][lane], h, Ha[j][lane]);

    // ---- phase 2: seeded scan + y ----
    #pragma unroll 1
    for (int cc = 0; cc < 4; ++cc) {
        const int c = w * 4 + cc;
        const size_t tix = tixb + (size_t)c * CL;
        float dtv = dtT[tix + lane];
        float uvf = (float)xcT[tix + lane];
        float zvf = (float)zT[tix + lane];
        float duv = dtv * uvf;
        float gD  = uvf * dpd;
        float wz  = siluf(zvf);
        const float* bp = dbl + (rowb + (size_t)c * CL) * 144 + 16 + lane;
        const float* cp = bp + 64;
        float yred[8];
        #pragma unroll
        for (int j = 0; j < 8; ++j) {
            float s[8];
            #pragma unroll
            for (int q = 0; q < 8; ++q) {
                const int t = 8*j + q;
                float dA = fexp2(rlane(dtv, t) * An2);
                h = fmaf(dA, h, rlane(duv, t) * bp[q * 144]);
                s[q] = h * cp[q * 144];
            }
            yred[j] = tree8(s, lane);
            bp += 8 * 144;
            cp += 8 * 144;
        }
        if ((lane & 7) == 0) {
            #pragma unroll
            for (int j = 0; j < 8; ++j) Ys[w][8*j + (lane >> 3)] = yred[j];
        }
        float y = (Ys[w][lane] + gD) * wz;
        yT[tix + lane] = (__bf16)y;
    }
}

extern "C" void kernel_launch(void* const* d_in, const int* in_sizes, int n_in,
                              void* d_out, int out_size, void* d_ws, size_t ws_size,
                              hipStream_t stream)
{
    const float* x      = (const float*)d_in[0];
    const float* ln_g   = (const float*)d_in[1];
    const float* ln_b   = (const float*)d_in[2];
    const float* in_w   = (const float*)d_in[3];
    const float* conv_w = (const float*)d_in[4];
    const float* conv_b = (const float*)d_in[5];
    const float* xp_w   = (const float*)d_in[6];
    const float* dt_w   = (const float*)d_in[7];
    const float* dt_b   = (const float*)d_in[8];
    const float* A_log  = (const float*)d_in[9];
    const float* Dp     = (const float*)d_in[10];
    const float* out_w  = (const float*)d_in[11];
    float* out = (float*)d_out;

    char* ws = (char*)d_ws;
    const size_t MB = 1u << 20;
    float*  xm   = (float*)(ws + 0*MB);    // conv input; dead after conv_tr
    float*  dtT  = (float*)(ws + 8*MB);    // [512][4096] fp32
    __bf16* xcbf = (__bf16*)(ws + 16*MB);  // conv out [4096][512]; dead after x_proj
    __bf16* yTb  = (__bf16*)(ws + 16*MB);  //   then scan out [512][4096]
    __bf16* xcT  = (__bf16*)(ws + 20*MB);  // [512][4096]
    __bf16* zbf  = (__bf16*)(ws + 24*MB);  // in_proj z; dead after conv_tr
    __bf16* ybf  = (__bf16*)(ws + 24*MB);  //   then y re-transposed [4096][512]
    __bf16* zT   = (__bf16*)(ws + 28*MB);  // [512][4096]
    float*  dblb = (float*)(ws + 40*MB);   // 2.25 MB
    __bf16* xnb  = (__bf16*)(ws + 43*MB);  // LN out (2 MB)
    __bf16* w_in  = (__bf16*)(ws + 45*MB);
    __bf16* w_xp  = (__bf16*)(ws + 46*MB);
    __bf16* w_out = (__bf16*)(ws + 46*MB + 512*1024);

    const int na = 2*1024*DM, nb = 2*144*DI, nc = 2*DM*DI;
    f2bf3<<<(na+nb+nc)/1024, 256, 0, stream>>>(
        in_w, w_in, na, xp_w, w_xp, nb, out_w, w_out, nc);

    for (int l = 0; l < 2; ++l) {
        const float* xin = (l == 0) ? x : out;
        ln_kernel<<<ROWS/4, 256, 0, stream>>>(xin, ln_g + l*DM, ln_b + l*DM, xnb);
        // in_proj -> xm fp32 | z bf16
        gemm_mfma<DM><<<dim3(1024/64, ROWS/64), 256, 0, stream>>>(
            xnb, w_in + (size_t)l*1024*DM, xm, zbf, nullptr, 1024, 1);
        // fused conv+silu (dual layout) + z transpose
        conv_tr_kernel<<<dim3(DI/64, ROWS/64), 256, 0, stream>>>(
            xm, conv_w + (size_t)l*DI*4, conv_b + (size_t)l*DI,
            (const u16*)zbf, xcbf, (u16*)xcT, (u16*)zT);
        // x_proj -> dbl fp32
        gemm_mfma<DI><<<dim3(3, ROWS/64), 256, 0, stream>>>(
            xcbf, w_xp + (size_t)l*144*DI, dblb, nullptr, nullptr, 144, 0);
        // dt projection, transposed fp32 out + softplus
        gemm_dt<<<dim3(DI/64, ROWS/64), 256, 0, stream>>>(
            dblb, 144, dt_w + (size_t)l*DI*16, dtT, dt_b + (size_t)l*DI);
        // fused chunked scan (p1 + carry + p2 in one launch)
        scan_fused2<<<BB*DI, 256, 0, stream>>>(
            dtT, xcT, zT, dblb, A_log + (size_t)l*DI*NST, Dp + (size_t)l*DI, yTb);
        transpose_bf<<<dim3(ROWS/64, DI/64), 256, 0, stream>>>(
            (const u16*)yTb, (u16*)ybf, ROWS, DI);
        // out_proj + residual
        gemm_mfma<DI><<<dim3(DM/64, ROWS/64), 256, 0, stream>>>(
            ybf, w_out + (size_t)l*DM*DI, out, nullptr, xin, DM, 2);
    }
}